// Round 3
// baseline (568.548 us; speedup 1.0000x reference)
//
#include <hip/hip_runtime.h>
#include <hip/hip_bf16.h>
#include <math.h>

// Problem constants
#define NN 20000
#define MM 20          // neighbors (same for che and vdw)
#define EE 20          // RBF size
#define HH 128
#define BB 200
#define NCONV 3
#define CHE_CUT 8.0f
#define VDW_CUT 12.0f
#define PI_F 3.14159265358979323846f
#define LOG2E_F 1.44269504088896340736f
#define LN2_F 0.69314718055994530942f

// __builtin_amdgcn_cvt_pkrtz / __builtin_amdgcn_fdot2 use __fp16 vectors
typedef __fp16 half2_t __attribute__((ext_vector_type(2)));
// MFMA f16 builtins use _Float16 vectors
typedef _Float16 f16x8 __attribute__((ext_vector_type(8)));
typedef float f32x4 __attribute__((ext_vector_type(4)));

// ---------------- helpers ---------------------------------------------------
__device__ __forceinline__ float exp2_(float x) {
#if __has_builtin(__builtin_amdgcn_exp2f)
    return __builtin_amdgcn_exp2f(x);
#else
    return exp2f(x);
#endif
}
__device__ __forceinline__ float log2_(float x) {
#if __has_builtin(__builtin_amdgcn_logf)
    return __builtin_amdgcn_logf(x);
#else
    return log2f(x);
#endif
}
__device__ __forceinline__ float rcp_(float x) {
#if __has_builtin(__builtin_amdgcn_rcpf)
    return __builtin_amdgcn_rcpf(x);
#else
    return 1.f / x;
#endif
}
__device__ __forceinline__ float med3_(float a, float b, float c) {
#if __has_builtin(__builtin_amdgcn_fmed3f)
    return __builtin_amdgcn_fmed3f(a, b, c);
#else
    return fminf(a, fmaxf(b, c));   // equivalent for our operand ordering
#endif
}
__device__ __forceinline__ float sp_(float x) {      // natural-domain softplus
    return (x > 15.f) ? x : LN2_F * log2_(1.f + exp2_(x * LOG2E_F));
}
__device__ __forceinline__ float fdot2_(half2_t a, half2_t b, float c) {
#if __has_builtin(__builtin_amdgcn_fdot2)
    return __builtin_amdgcn_fdot2(a, b, c, false);
#else
    return (float)a.x * (float)b.x + (float)a.y * (float)b.y + c;
#endif
}

// ---------------- prep: bc = (gb + fb @ gW_edge) * log2e --------------------
// bc layout: [l][half][gate*128+t] fp32
__global__ void prep_bias(const float* __restrict__ cfb, const float* __restrict__ cgW,
                          const float* __restrict__ cgb,
                          const float* __restrict__ vfb, const float* __restrict__ vgW,
                          const float* __restrict__ vgb, float* __restrict__ bc) {
    int half = blockIdx.y;
    int l = blockIdx.z;
    int j = threadIdx.x;         // 0..255
    const float* fb = half ? vfb : cfb;
    const float* gW = half ? vgW : cgW;
    const float* gb = half ? vgb : cgb;
    const float* gWe = gW + ((size_t)l * 384 + 128) * 256;
    const float* brow = fb + (size_t)l * HH;
    float acc = gb[(size_t)l * 256 + j];
    for (int k = 0; k < HH; ++k) acc = fmaf(brow[k], gWe[k * 256 + j], acc);
    bc[((size_t)l * 2 + half) * 256 + j] = acc * LOG2E_F;
}

// ---------------- prep: bwc — Wc=fW@gW_edge in MFMA B-fragment order --------
// PAIRED TILES: nt 0..7 = filt cols (t = nt*16+nc), nt 8..15 = core cols
// (same t) -> a wave computing tiles (p, 8+p) holds filt(t)/core(t) in ONE
// lane -> local cvt_pkrtz pack, no cross-lane traffic.
// k = e (0..19), pad 20..31 ZERO.
// bwc[l][h][nt(16)][lane(64)][8]: lane = (k>>3)*16 + nc, j = k&7
__global__ void prep_bwc(const float* __restrict__ cfW, const float* __restrict__ cgW,
                         const float* __restrict__ vfW, const float* __restrict__ vgW,
                         _Float16* __restrict__ bwc) {
    int nt = blockIdx.x;         // 0..15
    int half = blockIdx.y;
    int l = blockIdx.z;
    int tid = threadIdx.x;       // 0..511: k = tid>>4, nc = tid&15
    int k = tid >> 4, nc = tid & 15;
    int t = (nt & 7) * 16 + nc;          // 0..127
    int gcol = (nt >> 3) * 128 + t;      // filt: 0..127, core: 128..255
    const float* fW = half ? vfW : cfW;
    const float* gW = half ? vgW : cgW;
    const float* gWe = gW + ((size_t)l * 384 + 128) * 256;
    float val = 0.f;
    if (k < EE) {
        const float* frow = fW + ((size_t)l * EE + k) * HH;
        for (int kk = 0; kk < HH; ++kk) val = fmaf(frow[kk], gWe[kk * 256 + gcol], val);
        val *= LOG2E_F;
    }
    bwc[(((size_t)(l * 2 + half) * 16 + nt) * 64 + (k >> 3) * 16 + nc) * 8 + (k & 7)] = (_Float16)val;
}

// ---------------- prep: Bpk — B in MFMA B-fragment order, f16, x log2e ------
// column order (identity regions): [cheS|vdwS|cheY|vdwY]
__global__ void prep_bpk(const float* __restrict__ cgW, const float* __restrict__ vgW,
                         _Float16* __restrict__ bpk) {
    int i = blockIdx.x * 256 + threadIdx.x;
    if (i >= NCONV * 128 * 1024) return;
    int l = i >> 17;
    int rem = i & 131071;
    int k = rem >> 10;         // 0..127
    int c = rem & 1023;
    int half = (c >> 8) & 1;   // regions: che,vdw,che,vdw
    const float* src = half ? vgW : cgW;
    int grow = l * 384 + ((c < 512) ? k : 256 + k);
    float val = src[(size_t)grow * 256 + (c & 255)] * LOG2E_F;
    int nt = c >> 4, nc = c & 15;
    int s = k >> 5, kq = (k >> 3) & 3, j = k & 7;
    bpk[(size_t)l * 131072 + (((size_t)nt * 4 + s) * 64 + kq * 16 + nc) * 8 + j] = (_Float16)val;
}

// ---------------- embed: f32 nodes + f16 copy for the GEMM ------------------
__global__ void embed_kernel(const float* __restrict__ atoms, const float* __restrict__ W,
                             const float* __restrict__ bias, float* __restrict__ nodes,
                             _Float16* __restrict__ nodes_h) {
    int n = blockIdx.x, t = threadIdx.x;
    const float* arow = atoms + (size_t)n * 13;
    float acc = bias[t];
    #pragma unroll
    for (int k = 0; k < 13; ++k) acc = fmaf(arow[k], W[k * HH + t], acc);
    nodes[(size_t)n * HH + t] = acc;
    nodes_h[(size_t)n * HH + t] = (_Float16)acc;
}

// ---------------- rbf: write straight into per-node A-fragment order --------
// COMPACT layout, stride 640 f16 per (half,node):
//   tile0 (rows 0..15):  [lane(64)][8] f16 at offset 0    (lane = quad*16+row)
//   tile1c (rows 16..19): [quad(4)][row-16(4)][8] f16 at offset 512 (256 B)
// Rows 20..31 of tile 1 are structural zeros and are NOT stored; the edge
// kernel materializes them as zero lanes. k=20..31 zero padding lives in the
// v2/v3 quads and is re-written by data threads each launch (replay
// determinism — R9 tripwire).
__global__ void rbf_kernel(const float* __restrict__ che_fea, const float* __restrict__ vdw_fea,
                           _Float16* __restrict__ rfrag) {
    int i = blockIdx.x * blockDim.x + threadIdx.x;
    if (i >= 2 * NN * MM) return;
    bool isv = i >= NN * MM;
    int rem = isv ? i - NN * MM : i;
    int n = rem / MM, m = rem % MM;
    float d = isv ? vdw_fea[rem] : che_fea[rem];
    float cutoff = isv ? VDW_CUT : CHE_CUT;
    float x = d * (PI_F / cutoff);
    float s1 = sinf(x), c1 = cosf(x);
    float env = 0.5f * (c1 + 1.f);
    float scale = (d < cutoff) ? (env / d) : 0.f;
    float out[EE];
    float skm1 = 0.f, sk = s1;
    #pragma unroll
    for (int e = 0; e < EE; ++e) {
        out[e] = sk * scale;
        float nx = 2.f * c1 * sk - skm1;
        skm1 = sk; sk = nx;
    }
    _Float16* rf = rfrag + (size_t)(isv ? NN + n : n) * 640;
    f16x8 v0, v1, v2, v3;
    #pragma unroll
    for (int j = 0; j < 8; ++j) {
        v0[j] = (_Float16)out[j];
        v1[j] = (_Float16)out[8 + j];
        v2[j] = (j < 4) ? (_Float16)out[16 + j] : (_Float16)0.f;
        v3[j] = (_Float16)0.f;
    }
    if (m < 16) {
        _Float16* base = rf + m * 8;
        *(f16x8*)(base) = v0;             // quad 0 (k 0..7)
        *(f16x8*)(base + 128) = v1;       // quad 1 (k 8..15)
        *(f16x8*)(base + 256) = v2;       // quad 2 (k 16..23, 20+ zero)
        *(f16x8*)(base + 384) = v3;       // quad 3 (k 24..31, zero)
    } else {
        _Float16* base = rf + 512 + (m - 16) * 8;
        *(f16x8*)(base) = v0;
        *(f16x8*)(base + 32) = v1;
        *(f16x8*)(base + 64) = v2;
        *(f16x8*)(base + 96) = v3;
    }
}

// ---------------- SY GEMM via MFMA: [N,128]@[128,1024] -> Spk + Ypk f16x2 ---
// 625 blocks x 4 waves; M=32 rows/block, 2 row-tiles per wave (B fragments
// loaded once, used by both row-tiles -> B traffic halves vs 16-row blocks).
// Wave wv handles gate pair tiles (wv*16+p, wv*16+8+p), p=0..7 -> (filt,core)
// of one channel in SAME lane. wv 0: che-S, 1: vdw-S, 2: che-Y, 3: vdw-Y.
// All values pre-scaled by log2e.
__global__ __launch_bounds__(256)
void gemm_mfma(const _Float16* __restrict__ Ah, const _Float16* __restrict__ Bpk,
               half2_t* __restrict__ Spk, half2_t* __restrict__ Ypk) {
    int lane = threadIdx.x & 63;
    int wv = threadIdx.x >> 6;       // 0..3
    int m0 = blockIdx.x * 32;
    int la = lane & 15;
    int quad = lane >> 4;
    int k0 = quad * 8;

    f16x8 af0[4], af1[4];
    {
        const _Float16* arow = Ah + (size_t)(m0 + la) * 128 + k0;
        #pragma unroll
        for (int s = 0; s < 4; ++s) {
            af0[s] = *(const f16x8*)(arow + s * 32);
            af1[s] = *(const f16x8*)(arow + 2048 + s * 32);   // rows m0+16..m0+31
        }
    }

    const f16x8* bp = (const f16x8*)Bpk;
    int ntf0 = wv * 16;
    half2_t* dst = (wv & 2) ? Ypk : Spk;
    int wbase = (wv & 1) * 128 + la;

    f16x8 fb[4], cb[4], nfb[4], ncb[4];
    #pragma unroll
    for (int s = 0; s < 4; ++s) {
        fb[s] = bp[((size_t)ntf0 * 4 + s) * 64 + lane];
        cb[s] = bp[((size_t)(ntf0 + 8) * 4 + s) * 64 + lane];
    }
    for (int p = 0; p < 8; ++p) {
        if (p < 7) {
            #pragma unroll
            for (int s = 0; s < 4; ++s) {
                nfb[s] = bp[((size_t)(ntf0 + p + 1) * 4 + s) * 64 + lane];
                ncb[s] = bp[((size_t)(ntf0 + 9 + p) * 4 + s) * 64 + lane];
            }
        }
        f32x4 a0f = {0.f, 0.f, 0.f, 0.f};
        f32x4 a0c = {0.f, 0.f, 0.f, 0.f};
        f32x4 a1f = {0.f, 0.f, 0.f, 0.f};
        f32x4 a1c = {0.f, 0.f, 0.f, 0.f};
        #pragma unroll
        for (int s = 0; s < 4; ++s) {
            a0f = __builtin_amdgcn_mfma_f32_16x16x32_f16(af0[s], fb[s], a0f, 0, 0, 0);
            a0c = __builtin_amdgcn_mfma_f32_16x16x32_f16(af0[s], cb[s], a0c, 0, 0, 0);
            a1f = __builtin_amdgcn_mfma_f32_16x16x32_f16(af1[s], fb[s], a1f, 0, 0, 0);
            a1c = __builtin_amdgcn_mfma_f32_16x16x32_f16(af1[s], cb[s], a1c, 0, 0, 0);
        }
        int row = m0 + quad * 4;
        int word = wbase + p * 16;
        #pragma unroll
        for (int i = 0; i < 4; ++i) {
            dst[(size_t)(row + i) * 256 + word] = __builtin_amdgcn_cvt_pkrtz(a0f[i], a0c[i]);
            dst[(size_t)(row + 16 + i) * 256 + word] = __builtin_amdgcn_cvt_pkrtz(a1f[i], a1c[i]);
        }
        #pragma unroll
        for (int s = 0; s < 4; ++s) { fb[s] = nfb[s]; cb[s] = ncb[s]; }
    }
}

// ---------------- fused edge: MFMA contraction + LDS + gate + update --------
// Per block: one node, 4 WAVES (256 threads).
//
// STRUCTURE (this revision — latency-chain fix): the R0-R2 versions kept 20
// per-thread Ypk gathers in "registers"; at VGPR_Count=36 the compiler sank
// them into the phase-2 loop, producing a serial gather->use->gather chain
// (~10 x L2/L3 latency per wave) that dominated runtime. Now Y rows are
// staged cooperatively through LDS:
//   0) threads t<40 load the 40 neighbor indices -> sIdx (latency hidden
//      under phase 1).
//   1) phase 1: MFMA contraction -> G2 (pair layout), as before.
//   barrier
//   2) stage: 256 threads x 5 independent global_load_dwordx4 fetch the 40
//      needed Ypk rows (40x512B) -> Ys linear LDS. One pipelined latency
//      exposure per block instead of ten serialized ones.
//   barrier
//   3) phase 2: pure LDS+VALU gate chain (ds_read_b64 G pair + 2x b32 Y).
//
// G2 layout: row-PAIR packed. group-row g = h2*10 + (m>>1), parity = m&1,
// element index g*G2P + col*2 + parity. Phase-1 writes land as ds_write_b64
// pairs; phase-2 reads as ds_read_b64, conflict-free. Ys reads are
// stride-128-word b32 -> 2-way bank aliasing (free).
//
// NaN guard: p = med3(p_raw, gc, 25). Equivalent to `(gc>24)? gc : p` for
// all finite gc — for 24<gc<128, log2(1+exp2(gc))==gc exactly in f32; for
// gc>=128 exp2 overflows to inf and the median picks gc, so the
// fmaf(inf, 0, acc) NaN path (R15 post-mortem) remains impossible.
#define G2P 258   // half2 pitch per group-row
__global__ __launch_bounds__(256)
void edge_kernel(const float* __restrict__ nodes_in, float* __restrict__ nodes_out,
                 _Float16* __restrict__ nodes_h,
                 const half2_t* __restrict__ Spk, const half2_t* __restrict__ Ypk,
                 const _Float16* __restrict__ rfrag,
                 const int* __restrict__ idx_che, const int* __restrict__ idx_vdw,
                 const _Float16* __restrict__ bwc,  // this layer: [2][16][64][8]
                 const float* __restrict__ bC) {    // [2][256]
    __shared__ __align__(16) half2_t G2[20 * G2P]; // 20.6 KB
    __shared__ __align__(16) half2_t Ys[40 * 128]; // 20.5 KB — staged Y rows
    __shared__ float red[HH];                       // vdw partial sums
    __shared__ int sIdx[40];                        // neighbor indices
    int t = threadIdx.x;                            // 0..255
    int lane = t & 63;
    int wv = t >> 6;                                // 0..3
    int n = blockIdx.x;
    int h2 = t >> 7;                                // 0 = che group, 1 = vdw
    int tc = t & 127;                               // channel

    // ---- 0) neighbor indices: issue earliest, store to LDS after phase 1 --
    int myidx = 0;
    if (t < 40) {
        myidx = (t < MM) ? idx_che[(size_t)n * MM + t]
                         : idx_vdw[(size_t)n * MM + (t - MM)];
    }

    // per-thread loads used in phase 2 (issue early; small live range)
    half2_t spx = Spk[(size_t)n * 256 + h2 * 128 + tc];
    float old = (h2 == 0) ? nodes_in[(size_t)n * HH + tc] : 0.f;
    float sf = bC[h2 * 256 + tc] + (float)spx.x;
    float sc = bC[h2 * 256 + 128 + tc] + (float)spx.y;

    const half2_t ONE0 = {(__fp16)1.f, (__fp16)0.f};
    const half2_t ZERO1 = {(__fp16)0.f, (__fp16)1.f};
    int quad = lane >> 4;
    int cla = lane & 15;

    // ---- phase 1: wave wv computes half hw = wv>>1, tiles pg = (wv&1)*4+p
    {
        int hw = wv >> 1;
        const _Float16* rf = rfrag + (size_t)(hw * NN + n) * 640;
        f16x8 a0 = *(const f16x8*)(rf + lane * 8);
        f16x8 a1 = {};
        if (cla < 4) a1 = *(const f16x8*)(rf + 512 + (quad * 4 + cla) * 8);
        const f16x8* bw = (const f16x8*)bwc + ((size_t)hw * 16) * 64;
        #pragma unroll
        for (int p = 0; p < 4; ++p) {
            int pg = (wv & 1) * 4 + p;              // 0..7
            f16x8 bf = bw[(size_t)pg * 64 + lane];
            f16x8 bcfr = bw[(size_t)(8 + pg) * 64 + lane];
            f32x4 g0f = {0.f, 0.f, 0.f, 0.f};
            f32x4 g0c = {0.f, 0.f, 0.f, 0.f};
            f32x4 g1f = {0.f, 0.f, 0.f, 0.f};
            f32x4 g1c = {0.f, 0.f, 0.f, 0.f};
            g0f = __builtin_amdgcn_mfma_f32_16x16x32_f16(a0, bf, g0f, 0, 0, 0);
            g0c = __builtin_amdgcn_mfma_f32_16x16x32_f16(a0, bcfr, g0c, 0, 0, 0);
            g1f = __builtin_amdgcn_mfma_f32_16x16x32_f16(a1, bf, g1f, 0, 0, 0);
            g1c = __builtin_amdgcn_mfma_f32_16x16x32_f16(a1, bcfr, g1c, 0, 0, 0);
            int col = pg * 16 + cla;                // = channel col
            // rows quad*4+i -> (g = hw*10 + quad*2 + (i>>1), parity i&1)
            half2_t* w0 = &G2[(hw * 10 + quad * 2) * G2P + col * 2];
            w0[0] = __builtin_amdgcn_cvt_pkrtz(g0f[0], g0c[0]);
            w0[1] = __builtin_amdgcn_cvt_pkrtz(g0f[1], g0c[1]);
            half2_t* w1 = &G2[(hw * 10 + quad * 2 + 1) * G2P + col * 2];
            w1[0] = __builtin_amdgcn_cvt_pkrtz(g0f[2], g0c[2]);
            w1[1] = __builtin_amdgcn_cvt_pkrtz(g0f[3], g0c[3]);
            if (quad == 0) {                        // rows 16..19 -> g 8,9
                half2_t* w2 = &G2[(hw * 10 + 8) * G2P + col * 2];
                w2[0] = __builtin_amdgcn_cvt_pkrtz(g1f[0], g1c[0]);
                w2[1] = __builtin_amdgcn_cvt_pkrtz(g1f[1], g1c[1]);
                half2_t* w3 = &G2[(hw * 10 + 9) * G2P + col * 2];
                w3[0] = __builtin_amdgcn_cvt_pkrtz(g1f[2], g1c[2]);
                w3[1] = __builtin_amdgcn_cvt_pkrtz(g1f[3], g1c[3]);
            }
        }
    }
    if (t < 40) sIdx[t] = myidx;
    __syncthreads();

    // ---- 2) cooperative Y stage: 40 rows x 512B, 5 x 16B chunks/thread ----
    // chunk c = t + k*256: row = c>>5 (che rows 0..19, vdw 20..39),
    // off = c&31 (16B units). Global reads coalesced (32 lanes span a row);
    // all 5 loads independent -> single pipelined latency exposure.
    #pragma unroll
    for (int k = 0; k < 5; ++k) {
        int c = t + (k << 8);
        int row = c >> 5, off = c & 31;
        int jrow = sIdx[row];
        const f16x8* src = (const f16x8*)(Ypk + (size_t)jrow * 256 +
                                          ((row >= MM) ? 128 : 0) + off * 4);
        *(f16x8*)&Ys[row * 128 + off * 4] = *src;
    }
    __syncthreads();

    // ---- phase 2: 20-edge activation chain per thread, 2 edges/step ----
    float acc = 0.f;
    const half2_t* gq = G2 + (h2 * 10) * G2P + tc * 2;
    const half2_t* yq = Ys + (h2 * 20) * 128 + tc;
    #pragma unroll
    for (int mb = 0; mb < 10; ++mb) {
        half2_t ga = gq[mb * G2P];                  // edge m = 2*mb   (b64 pair)
        half2_t gb = gq[mb * G2P + 1];              // edge m = 2*mb+1
        half2_t gw0 = ga + yq[(2 * mb) * 128];      // packed f16 add
        half2_t gw1 = gb + yq[(2 * mb + 1) * 128];
        float gf0 = fdot2_(gw0, ONE0, sf);
        float gc0 = fdot2_(gw0, ZERO1, sc);
        float gf1 = fdot2_(gw1, ONE0, sf);
        float gc1 = fdot2_(gw1, ZERO1, sc);
        float u0 = rcp_(1.f + exp2_(-gf0));
        float u1 = rcp_(1.f + exp2_(-gf1));
        float p0 = log2_(1.f + exp2_(gc0));
        float p1 = log2_(1.f + exp2_(gc1));
        p0 = med3_(p0, gc0, 25.f);                  // inf*0 NaN guard (see note)
        p1 = med3_(p1, gc1, 25.f);
        acc = fmaf(p0, u0, acc);
        acc = fmaf(p1, u1, acc);
    }
    if (h2) red[tc] = acc;
    __syncthreads();
    if (!h2) {
        float res = sp_(fmaf(acc + red[tc], LN2_F, old));
        nodes_out[(size_t)n * HH + tc] = res;
        nodes_h[(size_t)n * HH + tc] = (_Float16)res;
    }
}

// ---------------- pooling + head MLP ---------------------------------------
__global__ void pool_kernel(const float* __restrict__ nodes, const int* __restrict__ num_atoms,
                            const float* __restrict__ fc1_W, const float* __restrict__ fc1_b,
                            const float* __restrict__ out_W, const float* __restrict__ out_b,
                            float* __restrict__ out) {
    __shared__ float sh[HH];
    __shared__ float red[HH];
    int b = blockIdx.x, t = threadIdx.x;
    int start = 0;
    for (int i = 0; i < b; ++i) start += num_atoms[i];
    int cnt = num_atoms[b];
    float sum = 0.f;
    for (int a = 0; a < cnt; ++a) sum += nodes[(size_t)(start + a) * HH + t];
    float mean = sum / (float)cnt;
    sh[t] = sp_(mean);
    __syncthreads();
    float o = fc1_b[t];
    #pragma unroll 4
    for (int k = 0; k < HH; ++k) o = fmaf(sh[k], fc1_W[k * HH + t], o);
    red[t] = sp_(o) * out_W[t];
    __syncthreads();
    if (t == 0) {
        float tot = 0.f;
        for (int k = 0; k < HH; ++k) tot += red[k];
        out[b] = tot + out_b[0];
    }
}

// ---------------- launch ----------------------------------------------------
extern "C" void kernel_launch(void* const* d_in, const int* in_sizes, int n_in,
                              void* d_out, int out_size, void* d_ws, size_t ws_size,
                              hipStream_t stream) {
    const float* atoms_embed   = (const float*)d_in[0];
    const float* che_nbrs_fea  = (const float*)d_in[1];
    const float* vdw_nbrs_fea  = (const float*)d_in[2];
    const int*   che_nbrs_idx  = (const int*)  d_in[3];
    const int*   vdw_nbrs_idx  = (const int*)  d_in[4];
    const int*   num_atoms     = (const int*)  d_in[5];
    const float* emb_W         = (const float*)d_in[6];
    const float* emb_b         = (const float*)d_in[7];
    const float* che_filter_W  = (const float*)d_in[8];
    const float* che_filter_b  = (const float*)d_in[9];
    const float* che_fc_W      = (const float*)d_in[10];
    const float* che_fc_b      = (const float*)d_in[11];
    const float* vdw_filter_W  = (const float*)d_in[12];
    const float* vdw_filter_b  = (const float*)d_in[13];
    const float* vdw_fc_W      = (const float*)d_in[14];
    const float* vdw_fc_b      = (const float*)d_in[15];
    const float* fc1_W         = (const float*)d_in[16];
    const float* fc1_b         = (const float*)d_in[17];
    const float* out_W         = (const float*)d_in[18];
    const float* out_b         = (const float*)d_in[19];
    float* out = (float*)d_out;

    // workspace layout (~130 MB)
    float* w = (float*)d_ws;
    float* nodesA   = w;                                       // NN*HH f32
    float* nodesB   = nodesA + (size_t)NN * HH;                // NN*HH f32
    _Float16* nodes_h = (_Float16*)(nodesB + (size_t)NN * HH); // NN*HH f16
    half2_t* Spk    = (half2_t*)(nodes_h + (size_t)NN * HH);   // NN*256 words
    half2_t* Ypk    = Spk + (size_t)NN * 256;                  // NN*256 words
    _Float16* rfrag = (_Float16*)(Ypk + (size_t)NN * 256);     // 2*NN*640 f16
    _Float16* bpk   = rfrag + (size_t)2 * NN * 640;            // NCONV*131072 f16
    _Float16* bwc   = bpk + (size_t)NCONV * 131072;            // NCONV*2*16*512 f16
    float* bc       = (float*)(bwc + (size_t)NCONV * 2 * 16 * 512); // NCONV*512 f32

    prep_bias<<<dim3(1, 2, NCONV), 256, 0, stream>>>(
        che_filter_b, che_fc_W, che_fc_b, vdw_filter_b, vdw_fc_W, vdw_fc_b, bc);
    prep_bwc<<<dim3(16, 2, NCONV), 512, 0, stream>>>(
        che_filter_W, che_fc_W, vdw_filter_W, vdw_fc_W, bwc);
    prep_bpk<<<(NCONV * 128 * 1024 + 255) / 256, 256, 0, stream>>>(che_fc_W, vdw_fc_W, bpk);
    embed_kernel<<<NN, HH, 0, stream>>>(atoms_embed, emb_W, emb_b, nodesA, nodes_h);
    rbf_kernel<<<(2 * NN * MM + 255) / 256, 256, 0, stream>>>(
        che_nbrs_fea, vdw_nbrs_fea, rfrag);

    float* cur = nodesA;
    float* nxt = nodesB;
    for (int l = 0; l < NCONV; ++l) {
        gemm_mfma<<<NN / 32, 256, 0, stream>>>(nodes_h, bpk + (size_t)l * 131072, Spk, Ypk);
        edge_kernel<<<NN, 256, 0, stream>>>(
            cur, nxt, nodes_h, Spk, Ypk, rfrag, che_nbrs_idx, vdw_nbrs_idx,
            bwc + (size_t)l * 2 * 16 * 512, bc + (size_t)l * 512);
        float* tmp = cur; cur = nxt; nxt = tmp;
    }

    pool_kernel<<<BB, HH, 0, stream>>>(cur, num_atoms, fc1_W, fc1_b, out_W, out_b, out);
}

// Round 4
// 455.415 us; speedup vs baseline: 1.2484x; 1.2484x over previous
//
#include <hip/hip_runtime.h>
#include <hip/hip_bf16.h>
#include <math.h>

// Problem constants
#define NN 20000
#define MM 20          // neighbors (same for che and vdw)
#define EE 20          // RBF size
#define HH 128
#define BB 200
#define NCONV 3
#define CHE_CUT 8.0f
#define VDW_CUT 12.0f
#define PI_F 3.14159265358979323846f
#define LOG2E_F 1.44269504088896340736f
#define LN2_F 0.69314718055994530942f

// __builtin_amdgcn_cvt_pkrtz / __builtin_amdgcn_fdot2 use __fp16 vectors
typedef __fp16 half2_t __attribute__((ext_vector_type(2)));
typedef __fp16 half4_t __attribute__((ext_vector_type(4)));
// MFMA f16 builtins use _Float16 vectors
typedef _Float16 f16x8 __attribute__((ext_vector_type(8)));
typedef float f32x4 __attribute__((ext_vector_type(4)));

// ---------------- helpers ---------------------------------------------------
__device__ __forceinline__ float exp2_(float x) {
#if __has_builtin(__builtin_amdgcn_exp2f)
    return __builtin_amdgcn_exp2f(x);
#else
    return exp2f(x);
#endif
}
__device__ __forceinline__ float log2_(float x) {
#if __has_builtin(__builtin_amdgcn_logf)
    return __builtin_amdgcn_logf(x);
#else
    return log2f(x);
#endif
}
__device__ __forceinline__ float rcp_(float x) {
#if __has_builtin(__builtin_amdgcn_rcpf)
    return __builtin_amdgcn_rcpf(x);
#else
    return 1.f / x;
#endif
}
__device__ __forceinline__ float med3_(float a, float b, float c) {
#if __has_builtin(__builtin_amdgcn_fmed3f)
    return __builtin_amdgcn_fmed3f(a, b, c);
#else
    return fminf(a, fmaxf(b, c));   // equivalent for our operand ordering
#endif
}
__device__ __forceinline__ float sp_(float x) {      // natural-domain softplus
    return (x > 15.f) ? x : LN2_F * log2_(1.f + exp2_(x * LOG2E_F));
}
__device__ __forceinline__ float fdot2_(half2_t a, half2_t b, float c) {
#if __has_builtin(__builtin_amdgcn_fdot2)
    return __builtin_amdgcn_fdot2(a, b, c, false);
#else
    return (float)a.x * (float)b.x + (float)a.y * (float)b.y + c;
#endif
}

// ---------------- prep: bc = (gb + fb @ gW_edge) * log2e --------------------
// bc layout: [l][half][gate*128+t] fp32
__global__ void prep_bias(const float* __restrict__ cfb, const float* __restrict__ cgW,
                          const float* __restrict__ cgb,
                          const float* __restrict__ vfb, const float* __restrict__ vgW,
                          const float* __restrict__ vgb, float* __restrict__ bc) {
    int half = blockIdx.y;
    int l = blockIdx.z;
    int j = threadIdx.x;         // 0..255
    const float* fb = half ? vfb : cfb;
    const float* gW = half ? vgW : cgW;
    const float* gb = half ? vgb : cgb;
    const float* gWe = gW + ((size_t)l * 384 + 128) * 256;
    const float* brow = fb + (size_t)l * HH;
    float acc = gb[(size_t)l * 256 + j];
    for (int k = 0; k < HH; ++k) acc = fmaf(brow[k], gWe[k * 256 + j], acc);
    bc[((size_t)l * 2 + half) * 256 + j] = acc * LOG2E_F;
}

// ---------------- prep: bwc — Wc=fW@gW_edge in MFMA B-fragment order --------
// PAIRED TILES: nt 0..7 = filt cols (t = nt*16+nc), nt 8..15 = core cols
// (same t) -> a wave computing tiles (p, 8+p) holds filt(t)/core(t) in ONE
// lane -> local cvt_pkrtz pack, no cross-lane traffic.
// k = e (0..19), pad 20..31 ZERO.
// bwc[l][h][nt(16)][lane(64)][8]: lane = (k>>3)*16 + nc, j = k&7
__global__ void prep_bwc(const float* __restrict__ cfW, const float* __restrict__ cgW,
                         const float* __restrict__ vfW, const float* __restrict__ vgW,
                         _Float16* __restrict__ bwc) {
    int nt = blockIdx.x;         // 0..15
    int half = blockIdx.y;
    int l = blockIdx.z;
    int tid = threadIdx.x;       // 0..511: k = tid>>4, nc = tid&15
    int k = tid >> 4, nc = tid & 15;
    int t = (nt & 7) * 16 + nc;          // 0..127
    int gcol = (nt >> 3) * 128 + t;      // filt: 0..127, core: 128..255
    const float* fW = half ? vfW : cfW;
    const float* gW = half ? vgW : cgW;
    const float* gWe = gW + ((size_t)l * 384 + 128) * 256;
    float val = 0.f;
    if (k < EE) {
        const float* frow = fW + ((size_t)l * EE + k) * HH;
        for (int kk = 0; kk < HH; ++kk) val = fmaf(frow[kk], gWe[kk * 256 + gcol], val);
        val *= LOG2E_F;
    }
    bwc[(((size_t)(l * 2 + half) * 16 + nt) * 64 + (k >> 3) * 16 + nc) * 8 + (k & 7)] = (_Float16)val;
}

// ---------------- prep: Bpk — B in MFMA B-fragment order, f16, x log2e ------
// column order (identity regions): [cheS|vdwS|cheY|vdwY]
__global__ void prep_bpk(const float* __restrict__ cgW, const float* __restrict__ vgW,
                         _Float16* __restrict__ bpk) {
    int i = blockIdx.x * 256 + threadIdx.x;
    if (i >= NCONV * 128 * 1024) return;
    int l = i >> 17;
    int rem = i & 131071;
    int k = rem >> 10;         // 0..127
    int c = rem & 1023;
    int half = (c >> 8) & 1;   // regions: che,vdw,che,vdw
    const float* src = half ? vgW : cgW;
    int grow = l * 384 + ((c < 512) ? k : 256 + k);
    float val = src[(size_t)grow * 256 + (c & 255)] * LOG2E_F;
    int nt = c >> 4, nc = c & 15;
    int s = k >> 5, kq = (k >> 3) & 3, j = k & 7;
    bpk[(size_t)l * 131072 + (((size_t)nt * 4 + s) * 64 + kq * 16 + nc) * 8 + j] = (_Float16)val;
}

// ---------------- embed: f32 nodes + f16 copy for the GEMM ------------------
__global__ void embed_kernel(const float* __restrict__ atoms, const float* __restrict__ W,
                             const float* __restrict__ bias, float* __restrict__ nodes,
                             _Float16* __restrict__ nodes_h) {
    int n = blockIdx.x, t = threadIdx.x;
    const float* arow = atoms + (size_t)n * 13;
    float acc = bias[t];
    #pragma unroll
    for (int k = 0; k < 13; ++k) acc = fmaf(arow[k], W[k * HH + t], acc);
    nodes[(size_t)n * HH + t] = acc;
    nodes_h[(size_t)n * HH + t] = (_Float16)acc;
}

// ---------------- rbf: write straight into per-node A-fragment order --------
// COMPACT layout, stride 640 f16 per (half,node):
//   tile0 (rows 0..15):  [lane(64)][8] f16 at offset 0    (lane = quad*16+row)
//   tile1c (rows 16..19): [quad(4)][row-16(4)][8] f16 at offset 512 (256 B)
// Rows 20..31 of tile 1 are structural zeros and are NOT stored; the edge
// kernel materializes them as zero lanes. k=20..31 zero padding lives in the
// v2/v3 quads and is re-written by data threads each launch (replay
// determinism — R9 tripwire).
__global__ void rbf_kernel(const float* __restrict__ che_fea, const float* __restrict__ vdw_fea,
                           _Float16* __restrict__ rfrag) {
    int i = blockIdx.x * blockDim.x + threadIdx.x;
    if (i >= 2 * NN * MM) return;
    bool isv = i >= NN * MM;
    int rem = isv ? i - NN * MM : i;
    int n = rem / MM, m = rem % MM;
    float d = isv ? vdw_fea[rem] : che_fea[rem];
    float cutoff = isv ? VDW_CUT : CHE_CUT;
    float x = d * (PI_F / cutoff);
    float s1 = sinf(x), c1 = cosf(x);
    float env = 0.5f * (c1 + 1.f);
    float scale = (d < cutoff) ? (env / d) : 0.f;
    float out[EE];
    float skm1 = 0.f, sk = s1;
    #pragma unroll
    for (int e = 0; e < EE; ++e) {
        out[e] = sk * scale;
        float nx = 2.f * c1 * sk - skm1;
        skm1 = sk; sk = nx;
    }
    _Float16* rf = rfrag + (size_t)(isv ? NN + n : n) * 640;
    f16x8 v0, v1, v2, v3;
    #pragma unroll
    for (int j = 0; j < 8; ++j) {
        v0[j] = (_Float16)out[j];
        v1[j] = (_Float16)out[8 + j];
        v2[j] = (j < 4) ? (_Float16)out[16 + j] : (_Float16)0.f;
        v3[j] = (_Float16)0.f;
    }
    if (m < 16) {
        _Float16* base = rf + m * 8;
        *(f16x8*)(base) = v0;             // quad 0 (k 0..7)
        *(f16x8*)(base + 128) = v1;       // quad 1 (k 8..15)
        *(f16x8*)(base + 256) = v2;       // quad 2 (k 16..23, 20+ zero)
        *(f16x8*)(base + 384) = v3;       // quad 3 (k 24..31, zero)
    } else {
        _Float16* base = rf + 512 + (m - 16) * 8;
        *(f16x8*)(base) = v0;
        *(f16x8*)(base + 32) = v1;
        *(f16x8*)(base + 64) = v2;
        *(f16x8*)(base + 96) = v3;
    }
}

// ---------------- SY GEMM via MFMA: [N,128]@[128,1024] -> Spk + Ypk f16x2 ---
// 625 blocks x 4 waves; M=32 rows/block, 2 row-tiles per wave (B fragments
// loaded once, used by both row-tiles -> B traffic halves vs 16-row blocks).
// Wave wv handles gate pair tiles (wv*16+p, wv*16+8+p), p=0..7 -> (filt,core)
// of one channel in SAME lane. wv 0: che-S, 1: vdw-S, 2: che-Y, 3: vdw-Y.
// All values pre-scaled by log2e.
__global__ __launch_bounds__(256)
void gemm_mfma(const _Float16* __restrict__ Ah, const _Float16* __restrict__ Bpk,
               half2_t* __restrict__ Spk, half2_t* __restrict__ Ypk) {
    int lane = threadIdx.x & 63;
    int wv = threadIdx.x >> 6;       // 0..3
    int m0 = blockIdx.x * 32;
    int la = lane & 15;
    int quad = lane >> 4;
    int k0 = quad * 8;

    f16x8 af0[4], af1[4];
    {
        const _Float16* arow = Ah + (size_t)(m0 + la) * 128 + k0;
        #pragma unroll
        for (int s = 0; s < 4; ++s) {
            af0[s] = *(const f16x8*)(arow + s * 32);
            af1[s] = *(const f16x8*)(arow + 2048 + s * 32);   // rows m0+16..m0+31
        }
    }

    const f16x8* bp = (const f16x8*)Bpk;
    int ntf0 = wv * 16;
    half2_t* dst = (wv & 2) ? Ypk : Spk;
    int wbase = (wv & 1) * 128 + la;

    f16x8 fb[4], cb[4], nfb[4], ncb[4];
    #pragma unroll
    for (int s = 0; s < 4; ++s) {
        fb[s] = bp[((size_t)ntf0 * 4 + s) * 64 + lane];
        cb[s] = bp[((size_t)(ntf0 + 8) * 4 + s) * 64 + lane];
    }
    for (int p = 0; p < 8; ++p) {
        if (p < 7) {
            #pragma unroll
            for (int s = 0; s < 4; ++s) {
                nfb[s] = bp[((size_t)(ntf0 + p + 1) * 4 + s) * 64 + lane];
                ncb[s] = bp[((size_t)(ntf0 + 9 + p) * 4 + s) * 64 + lane];
            }
        }
        f32x4 a0f = {0.f, 0.f, 0.f, 0.f};
        f32x4 a0c = {0.f, 0.f, 0.f, 0.f};
        f32x4 a1f = {0.f, 0.f, 0.f, 0.f};
        f32x4 a1c = {0.f, 0.f, 0.f, 0.f};
        #pragma unroll
        for (int s = 0; s < 4; ++s) {
            a0f = __builtin_amdgcn_mfma_f32_16x16x32_f16(af0[s], fb[s], a0f, 0, 0, 0);
            a0c = __builtin_amdgcn_mfma_f32_16x16x32_f16(af0[s], cb[s], a0c, 0, 0, 0);
            a1f = __builtin_amdgcn_mfma_f32_16x16x32_f16(af1[s], fb[s], a1f, 0, 0, 0);
            a1c = __builtin_amdgcn_mfma_f32_16x16x32_f16(af1[s], cb[s], a1c, 0, 0, 0);
        }
        int row = m0 + quad * 4;
        int word = wbase + p * 16;
        #pragma unroll
        for (int i = 0; i < 4; ++i) {
            dst[(size_t)(row + i) * 256 + word] = __builtin_amdgcn_cvt_pkrtz(a0f[i], a0c[i]);
            dst[(size_t)(row + 16 + i) * 256 + word] = __builtin_amdgcn_cvt_pkrtz(a1f[i], a1c[i]);
        }
        #pragma unroll
        for (int s = 0; s < 4; ++s) { fb[s] = nfb[s]; cb[s] = ncb[s]; }
    }
}

// ---------------- fused edge: MFMA contraction + LDS + gate + update --------
// Per block: one node, 4 WAVES (256 threads). Phase 1: 16 (half,pg)
// tile-pairs split across 4 waves -> G2. One barrier. Phase 2: threads
// t<128 handle 20 che edges of channel t; t>=128 the 20 vdw edges.
//
// LATENCY STRUCTURE (R4): R0-R2 let the compiler sink all 20 Y-gathers into
// the phase-2 loop (serial gather->use chain, ~10 L2 latencies/wave). R3
// staged them in LDS but paid 16KB LDS + a barrier -> occupancy 7->3
// blocks/CU and got SLOWER (abs VALU-busy is invariant ~85us; overlap
// tracks waves/CU). R4 keeps 7 blocks/CU and pipelines in REGISTERS:
// 4-deep rotation (prefetch next 4 gathers while computing current 4
// edges) -> live gather state is 4 VGPRs, exposed latency cut ~4x.
// launch_bounds(256,7) raises the VGPR cap to 73 so the allocator doesn't
// re-serialize to squeeze under 64.
//
// G2 layout: row-PAIR packed, G2P=260 (EVEN -> pair base 8B-aligned ->
// true ds_write_b64/ds_read_b64 via half4_t). group-row g = h2*10+(m>>1),
// parity m&1 at word g*G2P + col*2 + parity.
//
// NaN guard: p = med3(p_raw, gc, 25). Equivalent to `(gc>24)? gc : p` for
// all finite gc — for 24<gc<128, log2(1+exp2(gc))==gc exactly in f32; for
// gc>=128 exp2 overflows to inf and the median picks gc, so the
// fmaf(inf, 0, acc) NaN path (R15 post-mortem) remains impossible.
#define G2P 260   // half2 pitch per group-row (even: 8B-aligned pairs)
__global__ __launch_bounds__(256, 7)
void edge_kernel(const float* __restrict__ nodes_in, float* __restrict__ nodes_out,
                 _Float16* __restrict__ nodes_h,
                 const half2_t* __restrict__ Spk, const half2_t* __restrict__ Ypk,
                 const _Float16* __restrict__ rfrag,
                 const int* __restrict__ idx_che, const int* __restrict__ idx_vdw,
                 const _Float16* __restrict__ bwc,  // this layer: [2][16][64][8]
                 const float* __restrict__ bC) {    // [2][256]
    __shared__ __align__(16) half2_t G2[20 * G2P]; // 20.8 KB
    __shared__ float red[HH];                       // vdw partial sums
    int t = threadIdx.x;                            // 0..255
    int lane = t & 63;
    int wv = t >> 6;                                // 0..3
    int n = blockIdx.x;
    int h2 = t >> 7;                                // 0 = che group, 1 = vdw
    int tc = t & 127;                               // channel

    // ---- per-group neighbor indices: 5 x dwordx4 (rows are 80B, 16B-aligned)
    const int* idxp = h2 ? (idx_vdw + (size_t)n * MM) : (idx_che + (size_t)n * MM);
    int jx[MM];
    {
        const int4* ip = (const int4*)idxp;
        #pragma unroll
        for (int k = 0; k < 5; ++k) *(int4*)&jx[k * 4] = ip[k];
    }

    // ---- pipeline prologue: first 4 Y-gathers issue before phase 1 ----
    const half2_t* yb = Ypk + h2 * 128 + tc;
    half2_t y0 = yb[(size_t)jx[0] * 256];
    half2_t y1 = yb[(size_t)jx[1] * 256];
    half2_t y2 = yb[(size_t)jx[2] * 256];
    half2_t y3 = yb[(size_t)jx[3] * 256];

    half2_t spx = Spk[(size_t)n * 256 + h2 * 128 + tc];
    float old = (h2 == 0) ? nodes_in[(size_t)n * HH + tc] : 0.f;
    float sf = bC[h2 * 256 + tc] + (float)spx.x;
    float sc = bC[h2 * 256 + 128 + tc] + (float)spx.y;

    const half2_t ONE0 = {(__fp16)1.f, (__fp16)0.f};
    const half2_t ZERO1 = {(__fp16)0.f, (__fp16)1.f};
    int quad = lane >> 4;
    int cla = lane & 15;

    // ---- phase 1: wave wv computes half hw = wv>>1, tiles pg = (wv&1)*4+p
    {
        int hw = wv >> 1;
        const _Float16* rf = rfrag + (size_t)(hw * NN + n) * 640;
        f16x8 a0 = *(const f16x8*)(rf + lane * 8);
        f16x8 a1 = {};
        if (cla < 4) a1 = *(const f16x8*)(rf + 512 + (quad * 4 + cla) * 8);
        const f16x8* bw = (const f16x8*)bwc + ((size_t)hw * 16) * 64;
        #pragma unroll
        for (int p = 0; p < 4; ++p) {
            int pg = (wv & 1) * 4 + p;              // 0..7
            f16x8 bf = bw[(size_t)pg * 64 + lane];
            f16x8 bcfr = bw[(size_t)(8 + pg) * 64 + lane];
            f32x4 g0f = {0.f, 0.f, 0.f, 0.f};
            f32x4 g0c = {0.f, 0.f, 0.f, 0.f};
            f32x4 g1f = {0.f, 0.f, 0.f, 0.f};
            f32x4 g1c = {0.f, 0.f, 0.f, 0.f};
            g0f = __builtin_amdgcn_mfma_f32_16x16x32_f16(a0, bf, g0f, 0, 0, 0);
            g0c = __builtin_amdgcn_mfma_f32_16x16x32_f16(a0, bcfr, g0c, 0, 0, 0);
            g1f = __builtin_amdgcn_mfma_f32_16x16x32_f16(a1, bf, g1f, 0, 0, 0);
            g1c = __builtin_amdgcn_mfma_f32_16x16x32_f16(a1, bcfr, g1c, 0, 0, 0);
            int col = pg * 16 + cla;                // = channel col
            // rows quad*4+i -> (g = hw*10 + quad*2 + (i>>1), parity i&1)
            half4_t w0;
            w0.x = (__fp16)0.f;  // init to silence; all lanes overwritten below
            half2_t p0 = __builtin_amdgcn_cvt_pkrtz(g0f[0], g0c[0]);
            half2_t p1 = __builtin_amdgcn_cvt_pkrtz(g0f[1], g0c[1]);
            w0.x = p0.x; w0.y = p0.y; w0.z = p1.x; w0.w = p1.y;
            *(half4_t*)&G2[(hw * 10 + quad * 2) * G2P + col * 2] = w0;
            half4_t w1;
            half2_t p2 = __builtin_amdgcn_cvt_pkrtz(g0f[2], g0c[2]);
            half2_t p3 = __builtin_amdgcn_cvt_pkrtz(g0f[3], g0c[3]);
            w1.x = p2.x; w1.y = p2.y; w1.z = p3.x; w1.w = p3.y;
            *(half4_t*)&G2[(hw * 10 + quad * 2 + 1) * G2P + col * 2] = w1;
            if (quad == 0) {                        // rows 16..19 -> g 8,9
                half4_t w2;
                half2_t q0 = __builtin_amdgcn_cvt_pkrtz(g1f[0], g1c[0]);
                half2_t q1 = __builtin_amdgcn_cvt_pkrtz(g1f[1], g1c[1]);
                w2.x = q0.x; w2.y = q0.y; w2.z = q1.x; w2.w = q1.y;
                *(half4_t*)&G2[(hw * 10 + 8) * G2P + col * 2] = w2;
                half4_t w3;
                half2_t q2 = __builtin_amdgcn_cvt_pkrtz(g1f[2], g1c[2]);
                half2_t q3 = __builtin_amdgcn_cvt_pkrtz(g1f[3], g1c[3]);
                w3.x = q2.x; w3.y = q2.y; w3.z = q3.x; w3.w = q3.y;
                *(half4_t*)&G2[(hw * 10 + 9) * G2P + col * 2] = w3;
            }
        }
    }
    __syncthreads();

    // ---- phase 2: 20 edges, 4-deep software-pipelined gathers ----
    float acc = 0.f;
    const half2_t* gq = G2 + (h2 * 10) * G2P + tc * 2;
    #pragma unroll
    for (int cb = 0; cb < 5; ++cb) {
        half2_t n0 = {}, n1 = {}, n2 = {}, n3 = {};
        if (cb < 4) {                               // prefetch next 4 edges
            n0 = yb[(size_t)jx[cb * 4 + 4] * 256];
            n1 = yb[(size_t)jx[cb * 4 + 5] * 256];
            n2 = yb[(size_t)jx[cb * 4 + 6] * 256];
            n3 = yb[(size_t)jx[cb * 4 + 7] * 256];
        }
        half4_t gp0 = *(const half4_t*)(gq + (size_t)(2 * cb) * G2P);     // edges 4cb,4cb+1
        half4_t gp1 = *(const half4_t*)(gq + (size_t)(2 * cb + 1) * G2P); // edges 4cb+2,4cb+3
        half2_t gw0 = half2_t{gp0.x, gp0.y} + y0;
        half2_t gw1 = half2_t{gp0.z, gp0.w} + y1;
        half2_t gw2 = half2_t{gp1.x, gp1.y} + y2;
        half2_t gw3 = half2_t{gp1.z, gp1.w} + y3;
        float gf0 = fdot2_(gw0, ONE0, sf), gc0 = fdot2_(gw0, ZERO1, sc);
        float gf1 = fdot2_(gw1, ONE0, sf), gc1 = fdot2_(gw1, ZERO1, sc);
        float gf2 = fdot2_(gw2, ONE0, sf), gc2 = fdot2_(gw2, ZERO1, sc);
        float gf3 = fdot2_(gw3, ONE0, sf), gc3 = fdot2_(gw3, ZERO1, sc);
        float u0 = rcp_(1.f + exp2_(-gf0));
        float u1 = rcp_(1.f + exp2_(-gf1));
        float u2 = rcp_(1.f + exp2_(-gf2));
        float u3 = rcp_(1.f + exp2_(-gf3));
        float p0 = med3_(log2_(1.f + exp2_(gc0)), gc0, 25.f);
        float p1 = med3_(log2_(1.f + exp2_(gc1)), gc1, 25.f);
        float p2 = med3_(log2_(1.f + exp2_(gc2)), gc2, 25.f);
        float p3 = med3_(log2_(1.f + exp2_(gc3)), gc3, 25.f);
        acc = fmaf(p0, u0, acc);
        acc = fmaf(p1, u1, acc);
        acc = fmaf(p2, u2, acc);
        acc = fmaf(p3, u3, acc);
        y0 = n0; y1 = n1; y2 = n2; y3 = n3;
    }
    if (h2) red[tc] = acc;
    __syncthreads();
    if (!h2) {
        float res = sp_(fmaf(acc + red[tc], LN2_F, old));
        nodes_out[(size_t)n * HH + tc] = res;
        nodes_h[(size_t)n * HH + tc] = (_Float16)res;
    }
}

// ---------------- pooling + head MLP ---------------------------------------
__global__ void pool_kernel(const float* __restrict__ nodes, const int* __restrict__ num_atoms,
                            const float* __restrict__ fc1_W, const float* __restrict__ fc1_b,
                            const float* __restrict__ out_W, const float* __restrict__ out_b,
                            float* __restrict__ out) {
    __shared__ float sh[HH];
    __shared__ float red[HH];
    int b = blockIdx.x, t = threadIdx.x;
    int start = 0;
    for (int i = 0; i < b; ++i) start += num_atoms[i];
    int cnt = num_atoms[b];
    float sum = 0.f;
    for (int a = 0; a < cnt; ++a) sum += nodes[(size_t)(start + a) * HH + t];
    float mean = sum / (float)cnt;
    sh[t] = sp_(mean);
    __syncthreads();
    float o = fc1_b[t];
    #pragma unroll 4
    for (int k = 0; k < HH; ++k) o = fmaf(sh[k], fc1_W[k * HH + t], o);
    red[t] = sp_(o) * out_W[t];
    __syncthreads();
    if (t == 0) {
        float tot = 0.f;
        for (int k = 0; k < HH; ++k) tot += red[k];
        out[b] = tot + out_b[0];
    }
}

// ---------------- launch ----------------------------------------------------
extern "C" void kernel_launch(void* const* d_in, const int* in_sizes, int n_in,
                              void* d_out, int out_size, void* d_ws, size_t ws_size,
                              hipStream_t stream) {
    const float* atoms_embed   = (const float*)d_in[0];
    const float* che_nbrs_fea  = (const float*)d_in[1];
    const float* vdw_nbrs_fea  = (const float*)d_in[2];
    const int*   che_nbrs_idx  = (const int*)  d_in[3];
    const int*   vdw_nbrs_idx  = (const int*)  d_in[4];
    const int*   num_atoms     = (const int*)  d_in[5];
    const float* emb_W         = (const float*)d_in[6];
    const float* emb_b         = (const float*)d_in[7];
    const float* che_filter_W  = (const float*)d_in[8];
    const float* che_filter_b  = (const float*)d_in[9];
    const float* che_fc_W      = (const float*)d_in[10];
    const float* che_fc_b      = (const float*)d_in[11];
    const float* vdw_filter_W  = (const float*)d_in[12];
    const float* vdw_filter_b  = (const float*)d_in[13];
    const float* vdw_fc_W      = (const float*)d_in[14];
    const float* vdw_fc_b      = (const float*)d_in[15];
    const float* fc1_W         = (const float*)d_in[16];
    const float* fc1_b         = (const float*)d_in[17];
    const float* out_W         = (const float*)d_in[18];
    const float* out_b         = (const float*)d_in[19];
    float* out = (float*)d_out;

    // workspace layout (~130 MB)
    float* w = (float*)d_ws;
    float* nodesA   = w;                                       // NN*HH f32
    float* nodesB   = nodesA + (size_t)NN * HH;                // NN*HH f32
    _Float16* nodes_h = (_Float16*)(nodesB + (size_t)NN * HH); // NN*HH f16
    half2_t* Spk    = (half2_t*)(nodes_h + (size_t)NN * HH);   // NN*256 words
    half2_t* Ypk    = Spk + (size_t)NN * 256;                  // NN*256 words
    _Float16* rfrag = (_Float16*)(Ypk + (size_t)NN * 256);     // 2*NN*640 f16
    _Float16* bpk   = rfrag + (size_t)2 * NN * 640;            // NCONV*131072 f16
    _Float16* bwc   = bpk + (size_t)NCONV * 131072;            // NCONV*2*16*512 f16
    float* bc       = (float*)(bwc + (size_t)NCONV * 2 * 16 * 512); // NCONV*512 f32

    prep_bias<<<dim3(1, 2, NCONV), 256, 0, stream>>>(
        che_filter_b, che_fc_W, che_fc_b, vdw_filter_b, vdw_fc_W, vdw_fc_b, bc);
    prep_bwc<<<dim3(16, 2, NCONV), 512, 0, stream>>>(
        che_filter_W, che_fc_W, vdw_filter_W, vdw_fc_W, bwc);
    prep_bpk<<<(NCONV * 128 * 1024 + 255) / 256, 256, 0, stream>>>(che_fc_W, vdw_fc_W, bpk);
    embed_kernel<<<NN, HH, 0, stream>>>(atoms_embed, emb_W, emb_b, nodesA, nodes_h);
    rbf_kernel<<<(2 * NN * MM + 255) / 256, 256, 0, stream>>>(
        che_nbrs_fea, vdw_nbrs_fea, rfrag);

    float* cur = nodesA;
    float* nxt = nodesB;
    for (int l = 0; l < NCONV; ++l) {
        gemm_mfma<<<NN / 32, 256, 0, stream>>>(nodes_h, bpk + (size_t)l * 131072, Spk, Ypk);
        edge_kernel<<<NN, 256, 0, stream>>>(
            cur, nxt, nodes_h, Spk, Ypk, rfrag, che_nbrs_idx, vdw_nbrs_idx,
            bwc + (size_t)l * 2 * 16 * 512, bc + (size_t)l * 512);
        float* tmp = cur; cur = nxt; nxt = tmp;
    }

    pool_kernel<<<BB, HH, 0, stream>>>(cur, num_atoms, fc1_W, fc1_b, out_W, out_b, out);
}

// Round 6
// 448.893 us; speedup vs baseline: 1.2666x; 1.0145x over previous
//
#include <hip/hip_runtime.h>
#include <hip/hip_bf16.h>
#include <math.h>

// Problem constants
#define NN 20000
#define MM 20          // neighbors (same for che and vdw)
#define EE 20          // RBF size
#define HH 128
#define BB 200
#define NCONV 3
#define CHE_CUT 8.0f
#define VDW_CUT 12.0f
#define PI_F 3.14159265358979323846f
#define LOG2E_F 1.44269504088896340736f
#define LN2_F 0.69314718055994530942f

// __builtin_amdgcn_cvt_pkrtz / __builtin_amdgcn_fdot2 use __fp16 vectors
typedef __fp16 half2_t __attribute__((ext_vector_type(2)));
typedef __fp16 half4_t __attribute__((ext_vector_type(4)));
// MFMA f16 builtins use _Float16 vectors
typedef _Float16 f16x8 __attribute__((ext_vector_type(8)));
typedef float f32x4 __attribute__((ext_vector_type(4)));

// ---------------- helpers ---------------------------------------------------
__device__ __forceinline__ float exp2_(float x) {
#if __has_builtin(__builtin_amdgcn_exp2f)
    return __builtin_amdgcn_exp2f(x);
#else
    return exp2f(x);
#endif
}
__device__ __forceinline__ float log2_(float x) {
#if __has_builtin(__builtin_amdgcn_logf)
    return __builtin_amdgcn_logf(x);
#else
    return log2f(x);
#endif
}
__device__ __forceinline__ float rcp_(float x) {
#if __has_builtin(__builtin_amdgcn_rcpf)
    return __builtin_amdgcn_rcpf(x);
#else
    return 1.f / x;
#endif
}
__device__ __forceinline__ float med3_(float a, float b, float c) {
#if __has_builtin(__builtin_amdgcn_fmed3f)
    return __builtin_amdgcn_fmed3f(a, b, c);
#else
    return fminf(a, fmaxf(b, c));   // equivalent for our operand ordering
#endif
}
__device__ __forceinline__ float sp_(float x) {      // natural-domain softplus
    return (x > 15.f) ? x : LN2_F * log2_(1.f + exp2_(x * LOG2E_F));
}
__device__ __forceinline__ float fdot2_(half2_t a, half2_t b, float c) {
#if __has_builtin(__builtin_amdgcn_fdot2)
    return __builtin_amdgcn_fdot2(a, b, c, false);
#else
    return (float)a.x * (float)b.x + (float)a.y * (float)b.y + c;
#endif
}

// ---------------- prep: bc = (gb + fb @ gW_edge) * log2e --------------------
// bc layout: [l][half][gate*128+t] fp32
__global__ void prep_bias(const float* __restrict__ cfb, const float* __restrict__ cgW,
                          const float* __restrict__ cgb,
                          const float* __restrict__ vfb, const float* __restrict__ vgW,
                          const float* __restrict__ vgb, float* __restrict__ bc) {
    int half = blockIdx.y;
    int l = blockIdx.z;
    int j = threadIdx.x;         // 0..255
    const float* fb = half ? vfb : cfb;
    const float* gW = half ? vgW : cgW;
    const float* gb = half ? vgb : cgb;
    const float* gWe = gW + ((size_t)l * 384 + 128) * 256;
    const float* brow = fb + (size_t)l * HH;
    float acc = gb[(size_t)l * 256 + j];
    for (int k = 0; k < HH; ++k) acc = fmaf(brow[k], gWe[k * 256 + j], acc);
    bc[((size_t)l * 2 + half) * 256 + j] = acc * LOG2E_F;
}

// ---------------- prep: bwc — Wc=fW@gW_edge in MFMA B-fragment order --------
// PAIRED TILES: nt 0..7 = filt cols (t = nt*16+nc), nt 8..15 = core cols
// (same t) -> a wave computing tiles (p, 8+p) holds filt(t)/core(t) in ONE
// lane -> local cvt_pkrtz pack, no cross-lane traffic.
// k = e (0..19), pad 20..31 ZERO.
// bwc[l][h][nt(16)][lane(64)][8]: lane = (k>>3)*16 + nc, j = k&7
__global__ void prep_bwc(const float* __restrict__ cfW, const float* __restrict__ cgW,
                         const float* __restrict__ vfW, const float* __restrict__ vgW,
                         _Float16* __restrict__ bwc) {
    int nt = blockIdx.x;         // 0..15
    int half = blockIdx.y;
    int l = blockIdx.z;
    int tid = threadIdx.x;       // 0..511: k = tid>>4, nc = tid&15
    int k = tid >> 4, nc = tid & 15;
    int t = (nt & 7) * 16 + nc;          // 0..127
    int gcol = (nt >> 3) * 128 + t;      // filt: 0..127, core: 128..255
    const float* fW = half ? vfW : cfW;
    const float* gW = half ? vgW : cgW;
    const float* gWe = gW + ((size_t)l * 384 + 128) * 256;
    float val = 0.f;
    if (k < EE) {
        const float* frow = fW + ((size_t)l * EE + k) * HH;
        for (int kk = 0; kk < HH; ++kk) val = fmaf(frow[kk], gWe[kk * 256 + gcol], val);
        val *= LOG2E_F;
    }
    bwc[(((size_t)(l * 2 + half) * 16 + nt) * 64 + (k >> 3) * 16 + nc) * 8 + (k & 7)] = (_Float16)val;
}

// ---------------- prep: Bpk — B in MFMA B-fragment order, f16, x log2e ------
// column order (identity regions): [cheS|vdwS|cheY|vdwY]
__global__ void prep_bpk(const float* __restrict__ cgW, const float* __restrict__ vgW,
                         _Float16* __restrict__ bpk) {
    int i = blockIdx.x * 256 + threadIdx.x;
    if (i >= NCONV * 128 * 1024) return;
    int l = i >> 17;
    int rem = i & 131071;
    int k = rem >> 10;         // 0..127
    int c = rem & 1023;
    int half = (c >> 8) & 1;   // regions: che,vdw,che,vdw
    const float* src = half ? vgW : cgW;
    int grow = l * 384 + ((c < 512) ? k : 256 + k);
    float val = src[(size_t)grow * 256 + (c & 255)] * LOG2E_F;
    int nt = c >> 4, nc = c & 15;
    int s = k >> 5, kq = (k >> 3) & 3, j = k & 7;
    bpk[(size_t)l * 131072 + (((size_t)nt * 4 + s) * 64 + kq * 16 + nc) * 8 + j] = (_Float16)val;
}

// ---------------- embed: f32 nodes + f16 copy for the GEMM ------------------
__global__ void embed_kernel(const float* __restrict__ atoms, const float* __restrict__ W,
                             const float* __restrict__ bias, float* __restrict__ nodes,
                             _Float16* __restrict__ nodes_h) {
    int n = blockIdx.x, t = threadIdx.x;
    const float* arow = atoms + (size_t)n * 13;
    float acc = bias[t];
    #pragma unroll
    for (int k = 0; k < 13; ++k) acc = fmaf(arow[k], W[k * HH + t], acc);
    nodes[(size_t)n * HH + t] = acc;
    nodes_h[(size_t)n * HH + t] = (_Float16)acc;
}

// ---------------- rbf: write straight into per-node A-fragment order --------
// COMPACT layout, stride 640 f16 per (half,node):
//   tile0 (rows 0..15):  [lane(64)][8] f16 at offset 0    (lane = quad*16+row)
//   tile1c (rows 16..19): [quad(4)][row-16(4)][8] f16 at offset 512 (256 B)
// Rows 20..31 of tile 1 are structural zeros and are NOT stored; the edge
// kernel materializes them as zero lanes. k=20..31 zero padding lives in the
// v2/v3 quads and is re-written by data threads each launch (replay
// determinism — R9 tripwire).
__global__ void rbf_kernel(const float* __restrict__ che_fea, const float* __restrict__ vdw_fea,
                           _Float16* __restrict__ rfrag) {
    int i = blockIdx.x * blockDim.x + threadIdx.x;
    if (i >= 2 * NN * MM) return;
    bool isv = i >= NN * MM;
    int rem = isv ? i - NN * MM : i;
    int n = rem / MM, m = rem % MM;
    float d = isv ? vdw_fea[rem] : che_fea[rem];
    float cutoff = isv ? VDW_CUT : CHE_CUT;
    float x = d * (PI_F / cutoff);
    float s1 = sinf(x), c1 = cosf(x);
    float env = 0.5f * (c1 + 1.f);
    float scale = (d < cutoff) ? (env / d) : 0.f;
    float out[EE];
    float skm1 = 0.f, sk = s1;
    #pragma unroll
    for (int e = 0; e < EE; ++e) {
        out[e] = sk * scale;
        float nx = 2.f * c1 * sk - skm1;
        skm1 = sk; sk = nx;
    }
    _Float16* rf = rfrag + (size_t)(isv ? NN + n : n) * 640;
    f16x8 v0, v1, v2, v3;
    #pragma unroll
    for (int j = 0; j < 8; ++j) {
        v0[j] = (_Float16)out[j];
        v1[j] = (_Float16)out[8 + j];
        v2[j] = (j < 4) ? (_Float16)out[16 + j] : (_Float16)0.f;
        v3[j] = (_Float16)0.f;
    }
    if (m < 16) {
        _Float16* base = rf + m * 8;
        *(f16x8*)(base) = v0;             // quad 0 (k 0..7)
        *(f16x8*)(base + 128) = v1;       // quad 1 (k 8..15)
        *(f16x8*)(base + 256) = v2;       // quad 2 (k 16..23, 20+ zero)
        *(f16x8*)(base + 384) = v3;       // quad 3 (k 24..31, zero)
    } else {
        _Float16* base = rf + 512 + (m - 16) * 8;
        *(f16x8*)(base) = v0;
        *(f16x8*)(base + 32) = v1;
        *(f16x8*)(base + 64) = v2;
        *(f16x8*)(base + 96) = v3;
    }
}

// ---------------- SY GEMM via MFMA: [N,128]@[128,1024] -> Spk + Ypk f16x2 ---
// 625 blocks x 4 waves; M=32 rows/block, 2 row-tiles per wave. Wave wv
// handles gate pair tiles (wv*16+p, wv*16+8+p), p=0..7 -> (filt,core) of one
// channel in SAME lane. wv 0: che-S, 1: vdw-S, 2: che-Y, 3: vdw-Y.
//
// R5/R6: p-loop unrolled x2 with ALTERNATING B-fragment buffers (fb0/cb0 vs
// fb1/cb1). The old rotating-buffer version spent 32 v_mov per p-step (2x
// the MFMA count!) on fb[s]=nfb[s] copies and had only 1-deep prefetch
// against ~200cy L2 latency. Alternation removes all copies and lets the
// next tile's loads issue a full tile early. All values pre-scaled by log2e.
#define GEMM_TILE(P, FB, CB)                                                     \
    do {                                                                          \
        f32x4 a0f = {0.f,0.f,0.f,0.f}, a0c = {0.f,0.f,0.f,0.f};                   \
        f32x4 a1f = {0.f,0.f,0.f,0.f}, a1c = {0.f,0.f,0.f,0.f};                   \
        _Pragma("unroll")                                                         \
        for (int s = 0; s < 4; ++s) {                                             \
            a0f = __builtin_amdgcn_mfma_f32_16x16x32_f16(af0[s], FB[s], a0f, 0, 0, 0); \
            a0c = __builtin_amdgcn_mfma_f32_16x16x32_f16(af0[s], CB[s], a0c, 0, 0, 0); \
            a1f = __builtin_amdgcn_mfma_f32_16x16x32_f16(af1[s], FB[s], a1f, 0, 0, 0); \
            a1c = __builtin_amdgcn_mfma_f32_16x16x32_f16(af1[s], CB[s], a1c, 0, 0, 0); \
        }                                                                         \
        int row_ = m0 + quad * 4;                                                 \
        int word_ = wbase + (P) * 16;                                             \
        _Pragma("unroll")                                                         \
        for (int i = 0; i < 4; ++i) {                                             \
            dst[(size_t)(row_ + i) * 256 + word_] = __builtin_amdgcn_cvt_pkrtz(a0f[i], a0c[i]); \
            dst[(size_t)(row_ + 16 + i) * 256 + word_] = __builtin_amdgcn_cvt_pkrtz(a1f[i], a1c[i]); \
        }                                                                         \
    } while (0)

__global__ __launch_bounds__(256)
void gemm_mfma(const _Float16* __restrict__ Ah, const _Float16* __restrict__ Bpk,
               half2_t* __restrict__ Spk, half2_t* __restrict__ Ypk) {
    int lane = threadIdx.x & 63;
    int wv = threadIdx.x >> 6;       // 0..3
    int m0 = blockIdx.x * 32;
    int la = lane & 15;
    int quad = lane >> 4;
    int k0 = quad * 8;

    f16x8 af0[4], af1[4];
    {
        const _Float16* arow = Ah + (size_t)(m0 + la) * 128 + k0;
        #pragma unroll
        for (int s = 0; s < 4; ++s) {
            af0[s] = *(const f16x8*)(arow + s * 32);
            af1[s] = *(const f16x8*)(arow + 2048 + s * 32);   // rows m0+16..m0+31
        }
    }

    const f16x8* bp = (const f16x8*)Bpk;
    int ntf0 = wv * 16;
    half2_t* dst = (wv & 2) ? Ypk : Spk;
    int wbase = (wv & 1) * 128 + la;

    f16x8 fb0[4], cb0[4], fb1[4], cb1[4];
    #pragma unroll
    for (int s = 0; s < 4; ++s) {                      // tile p=0 -> buf0
        fb0[s] = bp[((size_t)ntf0 * 4 + s) * 64 + lane];
        cb0[s] = bp[((size_t)(ntf0 + 8) * 4 + s) * 64 + lane];
    }
    #pragma unroll
    for (int pp = 0; pp < 4; ++pp) {
        int p0 = 2 * pp, p1 = 2 * pp + 1;
        #pragma unroll
        for (int s = 0; s < 4; ++s) {                  // prefetch p1 -> buf1
            fb1[s] = bp[((size_t)(ntf0 + p1) * 4 + s) * 64 + lane];
            cb1[s] = bp[((size_t)(ntf0 + 8 + p1) * 4 + s) * 64 + lane];
        }
        GEMM_TILE(p0, fb0, cb0);
        if (pp < 3) {
            #pragma unroll
            for (int s = 0; s < 4; ++s) {              // prefetch p0+2 -> buf0
                fb0[s] = bp[((size_t)(ntf0 + p0 + 2) * 4 + s) * 64 + lane];
                cb0[s] = bp[((size_t)(ntf0 + 10 + p0) * 4 + s) * 64 + lane];
            }
        }
        GEMM_TILE(p1, fb1, cb1);
    }
}

// ---------------- fused edge: MFMA contraction + LDS + gate + update --------
// Per block: one node, 4 WAVES (256 threads). Phase 1: 16 (half,pg)
// tile-pairs split across 4 waves -> G2. One barrier. Phase 2: threads
// t<128 handle 20 che edges of channel t; t>=128 the 20 vdw edges.
//
// R4 latency structure retained: 4-deep register pipeline for the Y-gathers
// (prefetch next 4 while computing current 4) -> live gather state 4 VGPRs.
//
// R6 LDS: G2P = 256 EXACTLY (R5's 248 was a bug: each group-row needs
// 128 cols x 2 edges = 256 half2; writes at col*2 >= 248 overflowed into
// the next row -> NaN). G2 = 20*256*4 = 20480 B with NO separate red[]:
// the vdw partial-sum buffer is ALIASED onto G2's first 512 B, made safe
// by an extra __syncthreads() after phase 2 (all G2 reads drain before the
// red write). Total LDS = 20480 B = 160KB/8 -> 8 blocks/CU (R4: 21504 -> 7).
// Banks: phase-2 reads have wave-constant base -> bank pattern identical to
// the measured-0-conflict R4; phase-1 b64 writes go ~2-way -> 4-way on a
// small instruction count (free-ish per m136).
//
// NaN guard: p = med3(p_raw, gc, 25). Equivalent to `(gc>24)? gc : p` for
// all finite gc; keeps the fmaf(inf, 0, acc) NaN path (R15) impossible.
#define G2P 256   // half2 pitch per group-row — MUST be >= 256
__global__ __launch_bounds__(256, 8)
void edge_kernel(const float* __restrict__ nodes_in, float* __restrict__ nodes_out,
                 _Float16* __restrict__ nodes_h,
                 const half2_t* __restrict__ Spk, const half2_t* __restrict__ Ypk,
                 const _Float16* __restrict__ rfrag,
                 const int* __restrict__ idx_che, const int* __restrict__ idx_vdw,
                 const _Float16* __restrict__ bwc,  // this layer: [2][16][64][8]
                 const float* __restrict__ bC) {    // [2][256]
    __shared__ __align__(16) unsigned char smem[20 * G2P * 4]; // 20480 B total
    half2_t* G2 = (half2_t*)smem;
    float* red = (float*)smem;                       // aliased; see barrier note
    int t = threadIdx.x;                            // 0..255
    int lane = t & 63;
    int wv = t >> 6;                                // 0..3
    int n = blockIdx.x;
    int h2 = t >> 7;                                // 0 = che group, 1 = vdw
    int tc = t & 127;                               // channel

    // ---- per-group neighbor indices: 5 x dwordx4 (rows are 80B, 16B-aligned)
    const int* idxp = h2 ? (idx_vdw + (size_t)n * MM) : (idx_che + (size_t)n * MM);
    int jx[MM];
    {
        const int4* ip = (const int4*)idxp;
        #pragma unroll
        for (int k = 0; k < 5; ++k) *(int4*)&jx[k * 4] = ip[k];
    }

    // ---- pipeline prologue: first 4 Y-gathers issue before phase 1 ----
    const half2_t* yb = Ypk + h2 * 128 + tc;
    half2_t y0 = yb[(size_t)jx[0] * 256];
    half2_t y1 = yb[(size_t)jx[1] * 256];
    half2_t y2 = yb[(size_t)jx[2] * 256];
    half2_t y3 = yb[(size_t)jx[3] * 256];

    half2_t spx = Spk[(size_t)n * 256 + h2 * 128 + tc];
    float old = (h2 == 0) ? nodes_in[(size_t)n * HH + tc] : 0.f;
    float sf = bC[h2 * 256 + tc] + (float)spx.x;
    float sc = bC[h2 * 256 + 128 + tc] + (float)spx.y;

    const half2_t ONE0 = {(__fp16)1.f, (__fp16)0.f};
    const half2_t ZERO1 = {(__fp16)0.f, (__fp16)1.f};
    int quad = lane >> 4;
    int cla = lane & 15;

    // ---- phase 1: wave wv computes half hw = wv>>1, tiles pg = (wv&1)*4+p
    {
        int hw = wv >> 1;
        const _Float16* rf = rfrag + (size_t)(hw * NN + n) * 640;
        f16x8 a0 = *(const f16x8*)(rf + lane * 8);
        f16x8 a1 = {};
        if (cla < 4) a1 = *(const f16x8*)(rf + 512 + (quad * 4 + cla) * 8);
        const f16x8* bw = (const f16x8*)bwc + ((size_t)hw * 16) * 64;
        #pragma unroll
        for (int p = 0; p < 4; ++p) {
            int pg = (wv & 1) * 4 + p;              // 0..7
            f16x8 bf = bw[(size_t)pg * 64 + lane];
            f16x8 bcfr = bw[(size_t)(8 + pg) * 64 + lane];
            f32x4 g0f = {0.f, 0.f, 0.f, 0.f};
            f32x4 g0c = {0.f, 0.f, 0.f, 0.f};
            f32x4 g1f = {0.f, 0.f, 0.f, 0.f};
            f32x4 g1c = {0.f, 0.f, 0.f, 0.f};
            g0f = __builtin_amdgcn_mfma_f32_16x16x32_f16(a0, bf, g0f, 0, 0, 0);
            g0c = __builtin_amdgcn_mfma_f32_16x16x32_f16(a0, bcfr, g0c, 0, 0, 0);
            g1f = __builtin_amdgcn_mfma_f32_16x16x32_f16(a1, bf, g1f, 0, 0, 0);
            g1c = __builtin_amdgcn_mfma_f32_16x16x32_f16(a1, bcfr, g1c, 0, 0, 0);
            int col = pg * 16 + cla;                // = channel col, 0..127
            // rows quad*4+i -> (g = hw*10 + quad*2 + (i>>1), parity i&1)
            half4_t w0;
            half2_t p0 = __builtin_amdgcn_cvt_pkrtz(g0f[0], g0c[0]);
            half2_t p1 = __builtin_amdgcn_cvt_pkrtz(g0f[1], g0c[1]);
            w0.x = p0.x; w0.y = p0.y; w0.z = p1.x; w0.w = p1.y;
            *(half4_t*)&G2[(hw * 10 + quad * 2) * G2P + col * 2] = w0;
            half4_t w1;
            half2_t p2 = __builtin_amdgcn_cvt_pkrtz(g0f[2], g0c[2]);
            half2_t p3 = __builtin_amdgcn_cvt_pkrtz(g0f[3], g0c[3]);
            w1.x = p2.x; w1.y = p2.y; w1.z = p3.x; w1.w = p3.y;
            *(half4_t*)&G2[(hw * 10 + quad * 2 + 1) * G2P + col * 2] = w1;
            if (quad == 0) {                        // rows 16..19 -> g 8,9
                half4_t w2;
                half2_t q0 = __builtin_amdgcn_cvt_pkrtz(g1f[0], g1c[0]);
                half2_t q1 = __builtin_amdgcn_cvt_pkrtz(g1f[1], g1c[1]);
                w2.x = q0.x; w2.y = q0.y; w2.z = q1.x; w2.w = q1.y;
                *(half4_t*)&G2[(hw * 10 + 8) * G2P + col * 2] = w2;
                half4_t w3;
                half2_t q2 = __builtin_amdgcn_cvt_pkrtz(g1f[2], g1c[2]);
                half2_t q3 = __builtin_amdgcn_cvt_pkrtz(g1f[3], g1c[3]);
                w3.x = q2.x; w3.y = q2.y; w3.z = q3.x; w3.w = q3.y;
                *(half4_t*)&G2[(hw * 10 + 9) * G2P + col * 2] = w3;
            }
        }
    }
    __syncthreads();

    // ---- phase 2: 20 edges, 4-deep software-pipelined gathers ----
    float acc = 0.f;
    const half2_t* gq = G2 + (h2 * 10) * G2P + tc * 2;
    #pragma unroll
    for (int cb = 0; cb < 5; ++cb) {
        half2_t n0 = {}, n1 = {}, n2 = {}, n3 = {};
        if (cb < 4) {                               // prefetch next 4 edges
            n0 = yb[(size_t)jx[cb * 4 + 4] * 256];
            n1 = yb[(size_t)jx[cb * 4 + 5] * 256];
            n2 = yb[(size_t)jx[cb * 4 + 6] * 256];
            n3 = yb[(size_t)jx[cb * 4 + 7] * 256];
        }
        half4_t gp0 = *(const half4_t*)(gq + (size_t)(2 * cb) * G2P);     // edges 4cb,4cb+1
        half4_t gp1 = *(const half4_t*)(gq + (size_t)(2 * cb + 1) * G2P); // edges 4cb+2,4cb+3
        half2_t gw0 = half2_t{gp0.x, gp0.y} + y0;
        half2_t gw1 = half2_t{gp0.z, gp0.w} + y1;
        half2_t gw2 = half2_t{gp1.x, gp1.y} + y2;
        half2_t gw3 = half2_t{gp1.z, gp1.w} + y3;
        float gf0 = fdot2_(gw0, ONE0, sf), gc0 = fdot2_(gw0, ZERO1, sc);
        float gf1 = fdot2_(gw1, ONE0, sf), gc1 = fdot2_(gw1, ZERO1, sc);
        float gf2 = fdot2_(gw2, ONE0, sf), gc2 = fdot2_(gw2, ZERO1, sc);
        float gf3 = fdot2_(gw3, ONE0, sf), gc3 = fdot2_(gw3, ZERO1, sc);
        float u0 = rcp_(1.f + exp2_(-gf0));
        float u1 = rcp_(1.f + exp2_(-gf1));
        float u2 = rcp_(1.f + exp2_(-gf2));
        float u3 = rcp_(1.f + exp2_(-gf3));
        float p0 = med3_(log2_(1.f + exp2_(gc0)), gc0, 25.f);
        float p1 = med3_(log2_(1.f + exp2_(gc1)), gc1, 25.f);
        float p2 = med3_(log2_(1.f + exp2_(gc2)), gc2, 25.f);
        float p3 = med3_(log2_(1.f + exp2_(gc3)), gc3, 25.f);
        acc = fmaf(p0, u0, acc);
        acc = fmaf(p1, u1, acc);
        acc = fmaf(p2, u2, acc);
        acc = fmaf(p3, u3, acc);
        y0 = n0; y1 = n1; y2 = n2; y3 = n3;
    }
    // red[] aliases G2 — this barrier guarantees every thread's G2 reads
    // completed before any vdw thread overwrites the storage.
    __syncthreads();
    if (h2) red[tc] = acc;
    __syncthreads();
    if (!h2) {
        float res = sp_(fmaf(acc + red[tc], LN2_F, old));
        nodes_out[(size_t)n * HH + tc] = res;
        nodes_h[(size_t)n * HH + tc] = (_Float16)res;
    }
}

// ---------------- pooling + head MLP ---------------------------------------
__global__ void pool_kernel(const float* __restrict__ nodes, const int* __restrict__ num_atoms,
                            const float* __restrict__ fc1_W, const float* __restrict__ fc1_b,
                            const float* __restrict__ out_W, const float* __restrict__ out_b,
                            float* __restrict__ out) {
    __shared__ float sh[HH];
    __shared__ float red[HH];
    int b = blockIdx.x, t = threadIdx.x;
    int start = 0;
    for (int i = 0; i < b; ++i) start += num_atoms[i];
    int cnt = num_atoms[b];
    float sum = 0.f;
    for (int a = 0; a < cnt; ++a) sum += nodes[(size_t)(start + a) * HH + t];
    float mean = sum / (float)cnt;
    sh[t] = sp_(mean);
    __syncthreads();
    float o = fc1_b[t];
    #pragma unroll 4
    for (int k = 0; k < HH; ++k) o = fmaf(sh[k], fc1_W[k * HH + t], o);
    red[t] = sp_(o) * out_W[t];
    __syncthreads();
    if (t == 0) {
        float tot = 0.f;
        for (int k = 0; k < HH; ++k) tot += red[k];
        out[b] = tot + out_b[0];
    }
}

// ---------------- launch ----------------------------------------------------
extern "C" void kernel_launch(void* const* d_in, const int* in_sizes, int n_in,
                              void* d_out, int out_size, void* d_ws, size_t ws_size,
                              hipStream_t stream) {
    const float* atoms_embed   = (const float*)d_in[0];
    const float* che_nbrs_fea  = (const float*)d_in[1];
    const float* vdw_nbrs_fea  = (const float*)d_in[2];
    const int*   che_nbrs_idx  = (const int*)  d_in[3];
    const int*   vdw_nbrs_idx  = (const int*)  d_in[4];
    const int*   num_atoms     = (const int*)  d_in[5];
    const float* emb_W         = (const float*)d_in[6];
    const float* emb_b         = (const float*)d_in[7];
    const float* che_filter_W  = (const float*)d_in[8];
    const float* che_filter_b  = (const float*)d_in[9];
    const float* che_fc_W      = (const float*)d_in[10];
    const float* che_fc_b      = (const float*)d_in[11];
    const float* vdw_filter_W  = (const float*)d_in[12];
    const float* vdw_filter_b  = (const float*)d_in[13];
    const float* vdw_fc_W      = (const float*)d_in[14];
    const float* vdw_fc_b      = (const float*)d_in[15];
    const float* fc1_W         = (const float*)d_in[16];
    const float* fc1_b         = (const float*)d_in[17];
    const float* out_W         = (const float*)d_in[18];
    const float* out_b         = (const float*)d_in[19];
    float* out = (float*)d_out;

    // workspace layout (~130 MB)
    float* w = (float*)d_ws;
    float* nodesA   = w;                                       // NN*HH f32
    float* nodesB   = nodesA + (size_t)NN * HH;                // NN*HH f32
    _Float16* nodes_h = (_Float16*)(nodesB + (size_t)NN * HH); // NN*HH f16
    half2_t* Spk    = (half2_t*)(nodes_h + (size_t)NN * HH);   // NN*256 words
    half2_t* Ypk    = Spk + (size_t)NN * 256;                  // NN*256 words
    _Float16* rfrag = (_Float16*)(Ypk + (size_t)NN * 256);     // 2*NN*640 f16
    _Float16* bpk   = rfrag + (size_t)2 * NN * 640;            // NCONV*131072 f16
    _Float16* bwc   = bpk + (size_t)NCONV * 131072;            // NCONV*2*16*512 f16
    float* bc       = (float*)(bwc + (size_t)NCONV * 2 * 16 * 512); // NCONV*512 f32

    prep_bias<<<dim3(1, 2, NCONV), 256, 0, stream>>>(
        che_filter_b, che_fc_W, che_fc_b, vdw_filter_b, vdw_fc_W, vdw_fc_b, bc);
    prep_bwc<<<dim3(16, 2, NCONV), 512, 0, stream>>>(
        che_filter_W, che_fc_W, vdw_filter_W, vdw_fc_W, bwc);
    prep_bpk<<<(NCONV * 128 * 1024 + 255) / 256, 256, 0, stream>>>(che_fc_W, vdw_fc_W, bpk);
    embed_kernel<<<NN, HH, 0, stream>>>(atoms_embed, emb_W, emb_b, nodesA, nodes_h);
    rbf_kernel<<<(2 * NN * MM + 255) / 256, 256, 0, stream>>>(
        che_nbrs_fea, vdw_nbrs_fea, rfrag);

    float* cur = nodesA;
    float* nxt = nodesB;
    for (int l = 0; l < NCONV; ++l) {
        gemm_mfma<<<NN / 32, 256, 0, stream>>>(nodes_h, bpk + (size_t)l * 131072, Spk, Ypk);
        edge_kernel<<<NN, 256, 0, stream>>>(
            cur, nxt, nodes_h, Spk, Ypk, rfrag, che_nbrs_idx, vdw_nbrs_idx,
            bwc + (size_t)l * 2 * 16 * 512, bc + (size_t)l * 512);
        float* tmp = cur; cur = nxt; nxt = tmp;
    }

    pool_kernel<<<BB, HH, 0, stream>>>(cur, num_atoms, fc1_W, fc1_b, out_W, out_b, out);
}

// Round 7
// 447.485 us; speedup vs baseline: 1.2705x; 1.0031x over previous
//
#include <hip/hip_runtime.h>
#include <hip/hip_bf16.h>
#include <math.h>

// Problem constants
#define NN 20000
#define MM 20          // neighbors (same for che and vdw)
#define EE 20          // RBF size
#define HH 128
#define BB 200
#define NCONV 3
#define CHE_CUT 8.0f
#define VDW_CUT 12.0f
#define PI_F 3.14159265358979323846f
#define LOG2E_F 1.44269504088896340736f
#define LN2_F 0.69314718055994530942f

// __builtin_amdgcn_cvt_pkrtz / __builtin_amdgcn_fdot2 use __fp16 vectors
typedef __fp16 half2_t __attribute__((ext_vector_type(2)));
typedef __fp16 half4_t __attribute__((ext_vector_type(4)));
// MFMA f16 builtins use _Float16 vectors
typedef _Float16 f16x8 __attribute__((ext_vector_type(8)));
typedef float f32x4 __attribute__((ext_vector_type(4)));

// ---------------- helpers ---------------------------------------------------
__device__ __forceinline__ float exp2_(float x) {
#if __has_builtin(__builtin_amdgcn_exp2f)
    return __builtin_amdgcn_exp2f(x);
#else
    return exp2f(x);
#endif
}
__device__ __forceinline__ float log2_(float x) {
#if __has_builtin(__builtin_amdgcn_logf)
    return __builtin_amdgcn_logf(x);
#else
    return log2f(x);
#endif
}
__device__ __forceinline__ float rcp_(float x) {
#if __has_builtin(__builtin_amdgcn_rcpf)
    return __builtin_amdgcn_rcpf(x);
#else
    return 1.f / x;
#endif
}
__device__ __forceinline__ float med3_(float a, float b, float c) {
#if __has_builtin(__builtin_amdgcn_fmed3f)
    return __builtin_amdgcn_fmed3f(a, b, c);
#else
    return fminf(a, fmaxf(b, c));   // equivalent for our operand ordering
#endif
}
// HW sin/cos: v_sin_f32/v_cos_f32 take REVOLUTIONS (D = sin(S0*2pi)).
// Valid here because the argument is bounded (no range reduction needed).
__device__ __forceinline__ float sin_rev_(float rev) {
#if __has_builtin(__builtin_amdgcn_sinf)
    return __builtin_amdgcn_sinf(rev);
#else
    return sinf(rev * 6.28318530717958647693f);
#endif
}
__device__ __forceinline__ float cos_rev_(float rev) {
#if __has_builtin(__builtin_amdgcn_cosf)
    return __builtin_amdgcn_cosf(rev);
#else
    return cosf(rev * 6.28318530717958647693f);
#endif
}
__device__ __forceinline__ float sp_(float x) {      // natural-domain softplus
    return (x > 15.f) ? x : LN2_F * log2_(1.f + exp2_(x * LOG2E_F));
}
__device__ __forceinline__ float fdot2_(half2_t a, half2_t b, float c) {
#if __has_builtin(__builtin_amdgcn_fdot2)
    return __builtin_amdgcn_fdot2(a, b, c, false);
#else
    return (float)a.x * (float)b.x + (float)a.y * (float)b.y + c;
#endif
}

// ---------------- prep: bc = (gb + fb @ gW_edge) * log2e --------------------
// bc layout: [l][half][gate*128+t] fp32
__global__ void prep_bias(const float* __restrict__ cfb, const float* __restrict__ cgW,
                          const float* __restrict__ cgb,
                          const float* __restrict__ vfb, const float* __restrict__ vgW,
                          const float* __restrict__ vgb, float* __restrict__ bc) {
    int half = blockIdx.y;
    int l = blockIdx.z;
    int j = threadIdx.x;         // 0..255
    const float* fb = half ? vfb : cfb;
    const float* gW = half ? vgW : cgW;
    const float* gb = half ? vgb : cgb;
    const float* gWe = gW + ((size_t)l * 384 + 128) * 256;
    const float* brow = fb + (size_t)l * HH;
    float acc = gb[(size_t)l * 256 + j];
    for (int k = 0; k < HH; ++k) acc = fmaf(brow[k], gWe[k * 256 + j], acc);
    bc[((size_t)l * 2 + half) * 256 + j] = acc * LOG2E_F;
}

// ---------------- prep: bwc — Wc=fW@gW_edge in MFMA B-fragment order --------
// PAIRED TILES: nt 0..7 = filt cols (t = nt*16+nc), nt 8..15 = core cols
// (same t) -> a wave computing tiles (p, 8+p) holds filt(t)/core(t) in ONE
// lane -> local cvt_pkrtz pack, no cross-lane traffic.
// k = e (0..19), pad 20..31 ZERO.
// bwc[l][h][nt(16)][lane(64)][8]: lane = (k>>3)*16 + nc, j = k&7
__global__ void prep_bwc(const float* __restrict__ cfW, const float* __restrict__ cgW,
                         const float* __restrict__ vfW, const float* __restrict__ vgW,
                         _Float16* __restrict__ bwc) {
    int nt = blockIdx.x;         // 0..15
    int half = blockIdx.y;
    int l = blockIdx.z;
    int tid = threadIdx.x;       // 0..511: k = tid>>4, nc = tid&15
    int k = tid >> 4, nc = tid & 15;
    int t = (nt & 7) * 16 + nc;          // 0..127
    int gcol = (nt >> 3) * 128 + t;      // filt: 0..127, core: 128..255
    const float* fW = half ? vfW : cfW;
    const float* gW = half ? vgW : cgW;
    const float* gWe = gW + ((size_t)l * 384 + 128) * 256;
    float val = 0.f;
    if (k < EE) {
        const float* frow = fW + ((size_t)l * EE + k) * HH;
        for (int kk = 0; kk < HH; ++kk) val = fmaf(frow[kk], gWe[kk * 256 + gcol], val);
        val *= LOG2E_F;
    }
    bwc[(((size_t)(l * 2 + half) * 16 + nt) * 64 + (k >> 3) * 16 + nc) * 8 + (k & 7)] = (_Float16)val;
}

// ---------------- prep: Bpk — B in MFMA B-fragment order, f16, x log2e ------
// column order (identity regions): [cheS|vdwS|cheY|vdwY]
__global__ void prep_bpk(const float* __restrict__ cgW, const float* __restrict__ vgW,
                         _Float16* __restrict__ bpk) {
    int i = blockIdx.x * 256 + threadIdx.x;
    if (i >= NCONV * 128 * 1024) return;
    int l = i >> 17;
    int rem = i & 131071;
    int k = rem >> 10;         // 0..127
    int c = rem & 1023;
    int half = (c >> 8) & 1;   // regions: che,vdw,che,vdw
    const float* src = half ? vgW : cgW;
    int grow = l * 384 + ((c < 512) ? k : 256 + k);
    float val = src[(size_t)grow * 256 + (c & 255)] * LOG2E_F;
    int nt = c >> 4, nc = c & 15;
    int s = k >> 5, kq = (k >> 3) & 3, j = k & 7;
    bpk[(size_t)l * 131072 + (((size_t)nt * 4 + s) * 64 + kq * 16 + nc) * 8 + j] = (_Float16)val;
}

// ---------------- embed: f32 nodes + f16 copy for the GEMM ------------------
__global__ void embed_kernel(const float* __restrict__ atoms, const float* __restrict__ W,
                             const float* __restrict__ bias, float* __restrict__ nodes,
                             _Float16* __restrict__ nodes_h) {
    int n = blockIdx.x, t = threadIdx.x;
    const float* arow = atoms + (size_t)n * 13;
    float acc = bias[t];
    #pragma unroll
    for (int k = 0; k < 13; ++k) acc = fmaf(arow[k], W[k * HH + t], acc);
    nodes[(size_t)n * HH + t] = acc;
    nodes_h[(size_t)n * HH + t] = (_Float16)acc;
}

// ---------------- rbf: write straight into per-node A-fragment order --------
// COMPACT layout, stride 640 f16 per (half,node):
//   tile0 (rows 0..15):  [lane(64)][8] f16 at offset 0    (lane = quad*16+row)
//   tile1c (rows 16..19): [quad(4)][row-16(4)][8] f16 at offset 512 (256 B)
// Rows 20..31 of tile 1 are structural zeros and are NOT stored; the edge
// kernel materializes them as zero lanes. k=20..31 zero padding lives in the
// v2/v3 quads and is re-written by data threads each launch (replay
// determinism — R9 tripwire).
//
// R7: sinf/cosf (OCML libm, full range reduction, dozens of VALU ops) ->
// raw v_sin_f32/v_cos_f32. Argument x = d*pi/cutoff is bounded in
// [0, 1.1*pi], so rev = d/(2*cutoff) in [0, 0.55] is directly valid HW
// input (revolutions) — no reduction needed.
__global__ void rbf_kernel(const float* __restrict__ che_fea, const float* __restrict__ vdw_fea,
                           _Float16* __restrict__ rfrag) {
    int i = blockIdx.x * blockDim.x + threadIdx.x;
    if (i >= 2 * NN * MM) return;
    bool isv = i >= NN * MM;
    int rem = isv ? i - NN * MM : i;
    int n = rem / MM, m = rem % MM;
    float d = isv ? vdw_fea[rem] : che_fea[rem];
    float cutoff = isv ? VDW_CUT : CHE_CUT;
    float rev = d * (0.5f / cutoff);     // x/(2*pi), x = d*pi/cutoff
    float s1 = sin_rev_(rev);
    float c1 = cos_rev_(rev);
    float env = 0.5f * (c1 + 1.f);
    float scale = (d < cutoff) ? (env / d) : 0.f;
    float out[EE];
    float skm1 = 0.f, sk = s1;
    #pragma unroll
    for (int e = 0; e < EE; ++e) {
        out[e] = sk * scale;
        float nx = 2.f * c1 * sk - skm1;
        skm1 = sk; sk = nx;
    }
    _Float16* rf = rfrag + (size_t)(isv ? NN + n : n) * 640;
    f16x8 v0, v1, v2, v3;
    #pragma unroll
    for (int j = 0; j < 8; ++j) {
        v0[j] = (_Float16)out[j];
        v1[j] = (_Float16)out[8 + j];
        v2[j] = (j < 4) ? (_Float16)out[16 + j] : (_Float16)0.f;
        v3[j] = (_Float16)0.f;
    }
    if (m < 16) {
        _Float16* base = rf + m * 8;
        *(f16x8*)(base) = v0;             // quad 0 (k 0..7)
        *(f16x8*)(base + 128) = v1;       // quad 1 (k 8..15)
        *(f16x8*)(base + 256) = v2;       // quad 2 (k 16..23, 20+ zero)
        *(f16x8*)(base + 384) = v3;       // quad 3 (k 24..31, zero)
    } else {
        _Float16* base = rf + 512 + (m - 16) * 8;
        *(f16x8*)(base) = v0;
        *(f16x8*)(base + 32) = v1;
        *(f16x8*)(base + 64) = v2;
        *(f16x8*)(base + 96) = v3;
    }
}

// ---------------- SY GEMM via MFMA: [N,128]@[128,1024] -> Spk + Ypk f16x2 ---
// 625 blocks x 4 waves; M=32 rows/block, 2 row-tiles per wave. Wave wv
// handles gate pair tiles (wv*16+p, wv*16+8+p), p=0..7 -> (filt,core) of one
// channel in SAME lane. wv 0: che-S, 1: vdw-S, 2: che-Y, 3: vdw-Y.
//
// R5/R6: p-loop unrolled x2 with ALTERNATING B-fragment buffers (fb0/cb0 vs
// fb1/cb1) — removes 32 v_mov per p-step and gives full-tile-deep prefetch.
// All values pre-scaled by log2e.
#define GEMM_TILE(P, FB, CB)                                                     \
    do {                                                                          \
        f32x4 a0f = {0.f,0.f,0.f,0.f}, a0c = {0.f,0.f,0.f,0.f};                   \
        f32x4 a1f = {0.f,0.f,0.f,0.f}, a1c = {0.f,0.f,0.f,0.f};                   \
        _Pragma("unroll")                                                         \
        for (int s = 0; s < 4; ++s) {                                             \
            a0f = __builtin_amdgcn_mfma_f32_16x16x32_f16(af0[s], FB[s], a0f, 0, 0, 0); \
            a0c = __builtin_amdgcn_mfma_f32_16x16x32_f16(af0[s], CB[s], a0c, 0, 0, 0); \
            a1f = __builtin_amdgcn_mfma_f32_16x16x32_f16(af1[s], FB[s], a1f, 0, 0, 0); \
            a1c = __builtin_amdgcn_mfma_f32_16x16x32_f16(af1[s], CB[s], a1c, 0, 0, 0); \
        }                                                                         \
        int row_ = m0 + quad * 4;                                                 \
        int word_ = wbase + (P) * 16;                                             \
        _Pragma("unroll")                                                         \
        for (int i = 0; i < 4; ++i) {                                             \
            dst[(size_t)(row_ + i) * 256 + word_] = __builtin_amdgcn_cvt_pkrtz(a0f[i], a0c[i]); \
            dst[(size_t)(row_ + 16 + i) * 256 + word_] = __builtin_amdgcn_cvt_pkrtz(a1f[i], a1c[i]); \
        }                                                                         \
    } while (0)

__global__ __launch_bounds__(256)
void gemm_mfma(const _Float16* __restrict__ Ah, const _Float16* __restrict__ Bpk,
               half2_t* __restrict__ Spk, half2_t* __restrict__ Ypk) {
    int lane = threadIdx.x & 63;
    int wv = threadIdx.x >> 6;       // 0..3
    int m0 = blockIdx.x * 32;
    int la = lane & 15;
    int quad = lane >> 4;
    int k0 = quad * 8;

    f16x8 af0[4], af1[4];
    {
        const _Float16* arow = Ah + (size_t)(m0 + la) * 128 + k0;
        #pragma unroll
        for (int s = 0; s < 4; ++s) {
            af0[s] = *(const f16x8*)(arow + s * 32);
            af1[s] = *(const f16x8*)(arow + 2048 + s * 32);   // rows m0+16..m0+31
        }
    }

    const f16x8* bp = (const f16x8*)Bpk;
    int ntf0 = wv * 16;
    half2_t* dst = (wv & 2) ? Ypk : Spk;
    int wbase = (wv & 1) * 128 + la;

    f16x8 fb0[4], cb0[4], fb1[4], cb1[4];
    #pragma unroll
    for (int s = 0; s < 4; ++s) {                      // tile p=0 -> buf0
        fb0[s] = bp[((size_t)ntf0 * 4 + s) * 64 + lane];
        cb0[s] = bp[((size_t)(ntf0 + 8) * 4 + s) * 64 + lane];
    }
    #pragma unroll
    for (int pp = 0; pp < 4; ++pp) {
        int p0 = 2 * pp, p1 = 2 * pp + 1;
        #pragma unroll
        for (int s = 0; s < 4; ++s) {                  // prefetch p1 -> buf1
            fb1[s] = bp[((size_t)(ntf0 + p1) * 4 + s) * 64 + lane];
            cb1[s] = bp[((size_t)(ntf0 + 8 + p1) * 4 + s) * 64 + lane];
        }
        GEMM_TILE(p0, fb0, cb0);
        if (pp < 3) {
            #pragma unroll
            for (int s = 0; s < 4; ++s) {              // prefetch p0+2 -> buf0
                fb0[s] = bp[((size_t)(ntf0 + p0 + 2) * 4 + s) * 64 + lane];
                cb0[s] = bp[((size_t)(ntf0 + 10 + p0) * 4 + s) * 64 + lane];
            }
        }
        GEMM_TILE(p1, fb1, cb1);
    }
}

// ---------------- fused edge: MFMA contraction + LDS + gate + update --------
// Per block: one node, 4 WAVES (256 threads). Phase 1: 16 (half,pg)
// tile-pairs split across 4 waves -> G2. One barrier. Phase 2: threads
// t<128 handle 20 che edges of channel t; t>=128 the 20 vdw edges.
//
// R4 latency structure retained: 4-deep register pipeline for the Y-gathers
// (prefetch next 4 while computing current 4) -> live gather state 4 VGPRs.
//
// R6 LDS: G2P = 256 EXACTLY. G2 = 20*256*4 = 20480 B; the vdw partial-sum
// buffer red[] is ALIASED onto G2's first 512 B, made safe by an extra
// __syncthreads() after phase 2. Total LDS = 20480 B -> 8 blocks/CU.
//
// STATUS (R6 counters): 8 blocks/CU, VALUBusy 82%, 0 bank conflicts,
// VGPR 32. Edge is at its transcendental-throughput floor (4 trans ops x
// 102.4M edge-channels); further gains must come from other kernels.
//
// NaN guard: p = med3(p_raw, gc, 25). Equivalent to `(gc>24)? gc : p` for
// all finite gc; keeps the fmaf(inf, 0, acc) NaN path (R15) impossible.
#define G2P 256   // half2 pitch per group-row — MUST be >= 256
__global__ __launch_bounds__(256, 8)
void edge_kernel(const float* __restrict__ nodes_in, float* __restrict__ nodes_out,
                 _Float16* __restrict__ nodes_h,
                 const half2_t* __restrict__ Spk, const half2_t* __restrict__ Ypk,
                 const _Float16* __restrict__ rfrag,
                 const int* __restrict__ idx_che, const int* __restrict__ idx_vdw,
                 const _Float16* __restrict__ bwc,  // this layer: [2][16][64][8]
                 const float* __restrict__ bC) {    // [2][256]
    __shared__ __align__(16) unsigned char smem[20 * G2P * 4]; // 20480 B total
    half2_t* G2 = (half2_t*)smem;
    float* red = (float*)smem;                       // aliased; see barrier note
    int t = threadIdx.x;                            // 0..255
    int lane = t & 63;
    int wv = t >> 6;                                // 0..3
    int n = blockIdx.x;
    int h2 = t >> 7;                                // 0 = che group, 1 = vdw
    int tc = t & 127;                               // channel

    // ---- per-group neighbor indices: 5 x dwordx4 (rows are 80B, 16B-aligned)
    const int* idxp = h2 ? (idx_vdw + (size_t)n * MM) : (idx_che + (size_t)n * MM);
    int jx[MM];
    {
        const int4* ip = (const int4*)idxp;
        #pragma unroll
        for (int k = 0; k < 5; ++k) *(int4*)&jx[k * 4] = ip[k];
    }

    // ---- pipeline prologue: first 4 Y-gathers issue before phase 1 ----
    const half2_t* yb = Ypk + h2 * 128 + tc;
    half2_t y0 = yb[(size_t)jx[0] * 256];
    half2_t y1 = yb[(size_t)jx[1] * 256];
    half2_t y2 = yb[(size_t)jx[2] * 256];
    half2_t y3 = yb[(size_t)jx[3] * 256];

    half2_t spx = Spk[(size_t)n * 256 + h2 * 128 + tc];
    float old = (h2 == 0) ? nodes_in[(size_t)n * HH + tc] : 0.f;
    float sf = bC[h2 * 256 + tc] + (float)spx.x;
    float sc = bC[h2 * 256 + 128 + tc] + (float)spx.y;

    const half2_t ONE0 = {(__fp16)1.f, (__fp16)0.f};
    const half2_t ZERO1 = {(__fp16)0.f, (__fp16)1.f};
    int quad = lane >> 4;
    int cla = lane & 15;

    // ---- phase 1: wave wv computes half hw = wv>>1, tiles pg = (wv&1)*4+p
    {
        int hw = wv >> 1;
        const _Float16* rf = rfrag + (size_t)(hw * NN + n) * 640;
        f16x8 a0 = *(const f16x8*)(rf + lane * 8);
        f16x8 a1 = {};
        if (cla < 4) a1 = *(const f16x8*)(rf + 512 + (quad * 4 + cla) * 8);
        const f16x8* bw = (const f16x8*)bwc + ((size_t)hw * 16) * 64;
        #pragma unroll
        for (int p = 0; p < 4; ++p) {
            int pg = (wv & 1) * 4 + p;              // 0..7
            f16x8 bf = bw[(size_t)pg * 64 + lane];
            f16x8 bcfr = bw[(size_t)(8 + pg) * 64 + lane];
            f32x4 g0f = {0.f, 0.f, 0.f, 0.f};
            f32x4 g0c = {0.f, 0.f, 0.f, 0.f};
            f32x4 g1f = {0.f, 0.f, 0.f, 0.f};
            f32x4 g1c = {0.f, 0.f, 0.f, 0.f};
            g0f = __builtin_amdgcn_mfma_f32_16x16x32_f16(a0, bf, g0f, 0, 0, 0);
            g0c = __builtin_amdgcn_mfma_f32_16x16x32_f16(a0, bcfr, g0c, 0, 0, 0);
            g1f = __builtin_amdgcn_mfma_f32_16x16x32_f16(a1, bf, g1f, 0, 0, 0);
            g1c = __builtin_amdgcn_mfma_f32_16x16x32_f16(a1, bcfr, g1c, 0, 0, 0);
            int col = pg * 16 + cla;                // = channel col, 0..127
            // rows quad*4+i -> (g = hw*10 + quad*2 + (i>>1), parity i&1)
            half4_t w0;
            half2_t p0 = __builtin_amdgcn_cvt_pkrtz(g0f[0], g0c[0]);
            half2_t p1 = __builtin_amdgcn_cvt_pkrtz(g0f[1], g0c[1]);
            w0.x = p0.x; w0.y = p0.y; w0.z = p1.x; w0.w = p1.y;
            *(half4_t*)&G2[(hw * 10 + quad * 2) * G2P + col * 2] = w0;
            half4_t w1;
            half2_t p2 = __builtin_amdgcn_cvt_pkrtz(g0f[2], g0c[2]);
            half2_t p3 = __builtin_amdgcn_cvt_pkrtz(g0f[3], g0c[3]);
            w1.x = p2.x; w1.y = p2.y; w1.z = p3.x; w1.w = p3.y;
            *(half4_t*)&G2[(hw * 10 + quad * 2 + 1) * G2P + col * 2] = w1;
            if (quad == 0) {                        // rows 16..19 -> g 8,9
                half4_t w2;
                half2_t q0 = __builtin_amdgcn_cvt_pkrtz(g1f[0], g1c[0]);
                half2_t q1 = __builtin_amdgcn_cvt_pkrtz(g1f[1], g1c[1]);
                w2.x = q0.x; w2.y = q0.y; w2.z = q1.x; w2.w = q1.y;
                *(half4_t*)&G2[(hw * 10 + 8) * G2P + col * 2] = w2;
                half4_t w3;
                half2_t q2 = __builtin_amdgcn_cvt_pkrtz(g1f[2], g1c[2]);
                half2_t q3 = __builtin_amdgcn_cvt_pkrtz(g1f[3], g1c[3]);
                w3.x = q2.x; w3.y = q2.y; w3.z = q3.x; w3.w = q3.y;
                *(half4_t*)&G2[(hw * 10 + 9) * G2P + col * 2] = w3;
            }
        }
    }
    __syncthreads();

    // ---- phase 2: 20 edges, 4-deep software-pipelined gathers ----
    float acc = 0.f;
    const half2_t* gq = G2 + (h2 * 10) * G2P + tc * 2;
    #pragma unroll
    for (int cb = 0; cb < 5; ++cb) {
        half2_t n0 = {}, n1 = {}, n2 = {}, n3 = {};
        if (cb < 4) {                               // prefetch next 4 edges
            n0 = yb[(size_t)jx[cb * 4 + 4] * 256];
            n1 = yb[(size_t)jx[cb * 4 + 5] * 256];
            n2 = yb[(size_t)jx[cb * 4 + 6] * 256];
            n3 = yb[(size_t)jx[cb * 4 + 7] * 256];
        }
        half4_t gp0 = *(const half4_t*)(gq + (size_t)(2 * cb) * G2P);     // edges 4cb,4cb+1
        half4_t gp1 = *(const half4_t*)(gq + (size_t)(2 * cb + 1) * G2P); // edges 4cb+2,4cb+3
        half2_t gw0 = half2_t{gp0.x, gp0.y} + y0;
        half2_t gw1 = half2_t{gp0.z, gp0.w} + y1;
        half2_t gw2 = half2_t{gp1.x, gp1.y} + y2;
        half2_t gw3 = half2_t{gp1.z, gp1.w} + y3;
        float gf0 = fdot2_(gw0, ONE0, sf), gc0 = fdot2_(gw0, ZERO1, sc);
        float gf1 = fdot2_(gw1, ONE0, sf), gc1 = fdot2_(gw1, ZERO1, sc);
        float gf2 = fdot2_(gw2, ONE0, sf), gc2 = fdot2_(gw2, ZERO1, sc);
        float gf3 = fdot2_(gw3, ONE0, sf), gc3 = fdot2_(gw3, ZERO1, sc);
        float u0 = rcp_(1.f + exp2_(-gf0));
        float u1 = rcp_(1.f + exp2_(-gf1));
        float u2 = rcp_(1.f + exp2_(-gf2));
        float u3 = rcp_(1.f + exp2_(-gf3));
        float p0 = med3_(log2_(1.f + exp2_(gc0)), gc0, 25.f);
        float p1 = med3_(log2_(1.f + exp2_(gc1)), gc1, 25.f);
        float p2 = med3_(log2_(1.f + exp2_(gc2)), gc2, 25.f);
        float p3 = med3_(log2_(1.f + exp2_(gc3)), gc3, 25.f);
        acc = fmaf(p0, u0, acc);
        acc = fmaf(p1, u1, acc);
        acc = fmaf(p2, u2, acc);
        acc = fmaf(p3, u3, acc);
        y0 = n0; y1 = n1; y2 = n2; y3 = n3;
    }
    // red[] aliases G2 — this barrier guarantees every thread's G2 reads
    // completed before any vdw thread overwrites the storage.
    __syncthreads();
    if (h2) red[tc] = acc;
    __syncthreads();
    if (!h2) {
        float res = sp_(fmaf(acc + red[tc], LN2_F, old));
        nodes_out[(size_t)n * HH + tc] = res;
        nodes_h[(size_t)n * HH + tc] = (_Float16)res;
    }
}

// ---------------- pooling + head MLP ---------------------------------------
// R7: the serial prefix `for(i<b) start += num_atoms[i]` was a dependent
// load chain (~b x L2 latency; block 199 paid ~199 serial loads) and the
// t==0 final sum another 128-iter serial chain. Both replaced with parallel
// loads + LDS tree reductions.
__global__ void pool_kernel(const float* __restrict__ nodes, const int* __restrict__ num_atoms,
                            const float* __restrict__ fc1_W, const float* __restrict__ fc1_b,
                            const float* __restrict__ out_W, const float* __restrict__ out_b,
                            float* __restrict__ out) {
    __shared__ float sh[HH];
    __shared__ float red[HH];
    __shared__ int ipart[HH];
    int b = blockIdx.x, t = threadIdx.x;

    // ---- parallel prefix: start = sum_{i<b} num_atoms[i] ----
    int s = 0;
    for (int i = t; i < b; i += HH) s += num_atoms[i];
    ipart[t] = s;
    __syncthreads();
    #pragma unroll
    for (int st = HH / 2; st > 0; st >>= 1) {
        if (t < st) ipart[t] += ipart[t + st];
        __syncthreads();
    }
    int start = ipart[0];
    int cnt = num_atoms[b];

    float sum = 0.f;
    for (int a = 0; a < cnt; ++a) sum += nodes[(size_t)(start + a) * HH + t];
    float mean = sum / (float)cnt;
    sh[t] = sp_(mean);
    __syncthreads();
    float o = fc1_b[t];
    #pragma unroll 4
    for (int k = 0; k < HH; ++k) o = fmaf(sh[k], fc1_W[k * HH + t], o);
    red[t] = sp_(o) * out_W[t];
    __syncthreads();
    #pragma unroll
    for (int st = HH / 2; st > 0; st >>= 1) {
        if (t < st) red[t] += red[t + st];
        __syncthreads();
    }
    if (t == 0) out[b] = red[0] + out_b[0];
}

// ---------------- launch ----------------------------------------------------
extern "C" void kernel_launch(void* const* d_in, const int* in_sizes, int n_in,
                              void* d_out, int out_size, void* d_ws, size_t ws_size,
                              hipStream_t stream) {
    const float* atoms_embed   = (const float*)d_in[0];
    const float* che_nbrs_fea  = (const float*)d_in[1];
    const float* vdw_nbrs_fea  = (const float*)d_in[2];
    const int*   che_nbrs_idx  = (const int*)  d_in[3];
    const int*   vdw_nbrs_idx  = (const int*)  d_in[4];
    const int*   num_atoms     = (const int*)  d_in[5];
    const float* emb_W         = (const float*)d_in[6];
    const float* emb_b         = (const float*)d_in[7];
    const float* che_filter_W  = (const float*)d_in[8];
    const float* che_filter_b  = (const float*)d_in[9];
    const float* che_fc_W      = (const float*)d_in[10];
    const float* che_fc_b      = (const float*)d_in[11];
    const float* vdw_filter_W  = (const float*)d_in[12];
    const float* vdw_filter_b  = (const float*)d_in[13];
    const float* vdw_fc_W      = (const float*)d_in[14];
    const float* vdw_fc_b      = (const float*)d_in[15];
    const float* fc1_W         = (const float*)d_in[16];
    const float* fc1_b         = (const float*)d_in[17];
    const float* out_W         = (const float*)d_in[18];
    const float* out_b         = (const float*)d_in[19];
    float* out = (float*)d_out;

    // workspace layout (~130 MB)
    float* w = (float*)d_ws;
    float* nodesA   = w;                                       // NN*HH f32
    float* nodesB   = nodesA + (size_t)NN * HH;                // NN*HH f32
    _Float16* nodes_h = (_Float16*)(nodesB + (size_t)NN * HH); // NN*HH f16
    half2_t* Spk    = (half2_t*)(nodes_h + (size_t)NN * HH);   // NN*256 words
    half2_t* Ypk    = Spk + (size_t)NN * 256;                  // NN*256 words
    _Float16* rfrag = (_Float16*)(Ypk + (size_t)NN * 256);     // 2*NN*640 f16
    _Float16* bpk   = rfrag + (size_t)2 * NN * 640;            // NCONV*131072 f16
    _Float16* bwc   = bpk + (size_t)NCONV * 131072;            // NCONV*2*16*512 f16
    float* bc       = (float*)(bwc + (size_t)NCONV * 2 * 16 * 512); // NCONV*512 f32

    prep_bias<<<dim3(1, 2, NCONV), 256, 0, stream>>>(
        che_filter_b, che_fc_W, che_fc_b, vdw_filter_b, vdw_fc_W, vdw_fc_b, bc);
    prep_bwc<<<dim3(16, 2, NCONV), 512, 0, stream>>>(
        che_filter_W, che_fc_W, vdw_filter_W, vdw_fc_W, bwc);
    prep_bpk<<<(NCONV * 128 * 1024 + 255) / 256, 256, 0, stream>>>(che_fc_W, vdw_fc_W, bpk);
    embed_kernel<<<NN, HH, 0, stream>>>(atoms_embed, emb_W, emb_b, nodesA, nodes_h);
    rbf_kernel<<<(2 * NN * MM + 255) / 256, 256, 0, stream>>>(
        che_nbrs_fea, vdw_nbrs_fea, rfrag);

    float* cur = nodesA;
    float* nxt = nodesB;
    for (int l = 0; l < NCONV; ++l) {
        gemm_mfma<<<NN / 32, 256, 0, stream>>>(nodes_h, bpk + (size_t)l * 131072, Spk, Ypk);
        edge_kernel<<<NN, 256, 0, stream>>>(
            cur, nxt, nodes_h, Spk, Ypk, rfrag, che_nbrs_idx, vdw_nbrs_idx,
            bwc + (size_t)l * 2 * 16 * 512, bc + (size_t)l * 512);
        float* tmp = cur; cur = nxt; nxt = tmp;
    }

    pool_kernel<<<BB, HH, 0, stream>>>(cur, num_atoms, fc1_W, fc1_b, out_W, out_b, out);
}

// Round 8
// 420.140 us; speedup vs baseline: 1.3532x; 1.0651x over previous
//
#include <hip/hip_runtime.h>
#include <hip/hip_bf16.h>
#include <math.h>

// Problem constants
#define NN 20000
#define MM 20          // neighbors (same for che and vdw)
#define EE 20          // RBF size
#define HH 128
#define BB 200
#define NCONV 3
#define CHE_CUT 8.0f
#define VDW_CUT 12.0f
#define PI_F 3.14159265358979323846f
#define LOG2E_F 1.44269504088896340736f
#define LN2_F 0.69314718055994530942f

// __builtin_amdgcn_cvt_pkrtz / __builtin_amdgcn_fdot2 use __fp16 vectors
typedef __fp16 half2_t __attribute__((ext_vector_type(2)));
typedef __fp16 half4_t __attribute__((ext_vector_type(4)));
// MFMA f16 builtins use _Float16 vectors
typedef _Float16 f16x8 __attribute__((ext_vector_type(8)));
typedef float f32x4 __attribute__((ext_vector_type(4)));

// ---------------- helpers ---------------------------------------------------
__device__ __forceinline__ float exp2_(float x) {
#if __has_builtin(__builtin_amdgcn_exp2f)
    return __builtin_amdgcn_exp2f(x);
#else
    return exp2f(x);
#endif
}
__device__ __forceinline__ float log2_(float x) {
#if __has_builtin(__builtin_amdgcn_logf)
    return __builtin_amdgcn_logf(x);
#else
    return log2f(x);
#endif
}
__device__ __forceinline__ float rcp_(float x) {
#if __has_builtin(__builtin_amdgcn_rcpf)
    return __builtin_amdgcn_rcpf(x);
#else
    return 1.f / x;
#endif
}
__device__ __forceinline__ float med3_(float a, float b, float c) {
#if __has_builtin(__builtin_amdgcn_fmed3f)
    return __builtin_amdgcn_fmed3f(a, b, c);
#else
    return fminf(a, fmaxf(b, c));   // equivalent for our operand ordering
#endif
}
// HW sin/cos: v_sin_f32/v_cos_f32 take REVOLUTIONS (D = sin(S0*2pi)).
// Valid here because the argument is bounded (no range reduction needed).
__device__ __forceinline__ float sin_rev_(float rev) {
#if __has_builtin(__builtin_amdgcn_sinf)
    return __builtin_amdgcn_sinf(rev);
#else
    return sinf(rev * 6.28318530717958647693f);
#endif
}
__device__ __forceinline__ float cos_rev_(float rev) {
#if __has_builtin(__builtin_amdgcn_cosf)
    return __builtin_amdgcn_cosf(rev);
#else
    return cosf(rev * 6.28318530717958647693f);
#endif
}
__device__ __forceinline__ float sp_(float x) {      // natural-domain softplus
    return (x > 15.f) ? x : LN2_F * log2_(1.f + exp2_(x * LOG2E_F));
}
__device__ __forceinline__ float fdot2_(half2_t a, half2_t b, float c) {
#if __has_builtin(__builtin_amdgcn_fdot2)
    return __builtin_amdgcn_fdot2(a, b, c, false);
#else
    return (float)a.x * (float)b.x + (float)a.y * (float)b.y + c;
#endif
}

// ---------------- mega_prep: 5 independent front-end kernels in ONE launch ---
// R8: the tail was dominated by ~10us/dispatch launch overhead (12 launches;
// R7's rbf/pool optimizations moved nothing). prep_bias, prep_bwc, prep_bpk,
// embed, rbf are mutually independent and barrier-free -> block-range
// partition in one launch. Bodies identical to the R7 standalone kernels
// except index mapping (bwc: 512 -> 256 threads via k-range split sub).
//
// Block ranges:
#define MB_BIAS 6            // bias: bi 0..5           (half = bi&1, l = bi>>1)
#define MB_BWC  192          // bwc:  2 sub x 16 nt x 2 half x 3 l
#define MB_BPK  1536         // bpk:  393216 elems / 256
#define MB_EMB  10000        // embed: 2 nodes/block
#define MB_RBF  3125         // rbf:  800000 elems / 256
#define OFF_BWC (MB_BIAS)
#define OFF_BPK (OFF_BWC + MB_BWC)
#define OFF_EMB (OFF_BPK + MB_BPK)
#define OFF_RBF (OFF_EMB + MB_EMB)
#define MB_TOTAL (OFF_RBF + MB_RBF)

__global__ __launch_bounds__(256)
void mega_prep(const float* __restrict__ cfb, const float* __restrict__ cgW,
               const float* __restrict__ cgb,
               const float* __restrict__ vfb, const float* __restrict__ vgW,
               const float* __restrict__ vgb,
               const float* __restrict__ cfW, const float* __restrict__ vfW,
               const float* __restrict__ atoms, const float* __restrict__ embW,
               const float* __restrict__ embB,
               const float* __restrict__ che_fea, const float* __restrict__ vdw_fea,
               float* __restrict__ bc, _Float16* __restrict__ bwc,
               _Float16* __restrict__ bpk,
               float* __restrict__ nodes, _Float16* __restrict__ nodes_h,
               _Float16* __restrict__ rfrag) {
    int bi = blockIdx.x;
    int tid = threadIdx.x;

    if (bi < MB_BIAS) {
        // ---- prep_bias: bc = (gb + fb @ gW_edge) * log2e; [l][half][512] ----
        int half = bi & 1, l = bi >> 1;
        const float* fb = half ? vfb : cfb;
        const float* gW = half ? vgW : cgW;
        const float* gb = half ? vgb : cgb;
        const float* gWe = gW + ((size_t)l * 384 + 128) * 256;
        const float* brow = fb + (size_t)l * HH;
        float acc = gb[(size_t)l * 256 + tid];
        for (int k = 0; k < HH; ++k) acc = fmaf(brow[k], gWe[k * 256 + tid], acc);
        bc[((size_t)l * 2 + half) * 256 + tid] = acc * LOG2E_F;
        return;
    }
    if (bi < OFF_BPK) {
        // ---- prep_bwc: Wc = fW @ gW_edge in B-fragment order ----
        // PAIRED TILES: nt 0..7 filt cols, nt 8..15 core cols; k=e 0..19,
        // pad 20..31 zero. bwc[l][h][nt][lane(64)][8]: lane=(k>>3)*16+nc.
        int b2 = bi - OFF_BWC;
        int sub = b2 & 1;                       // k-range half: 0..15 / 16..31
        int nt = (b2 >> 1) & 15;
        int half = (b2 >> 5) & 1;
        int l = b2 >> 6;
        int k = sub * 16 + (tid >> 4), nc = tid & 15;
        int t = (nt & 7) * 16 + nc;
        int gcol = (nt >> 3) * 128 + t;
        const float* fW = half ? vfW : cfW;
        const float* gW = half ? vgW : cgW;
        const float* gWe = gW + ((size_t)l * 384 + 128) * 256;
        float val = 0.f;
        if (k < EE) {
            const float* frow = fW + ((size_t)l * EE + k) * HH;
            for (int kk = 0; kk < HH; ++kk) val = fmaf(frow[kk], gWe[kk * 256 + gcol], val);
            val *= LOG2E_F;
        }
        bwc[(((size_t)(l * 2 + half) * 16 + nt) * 64 + (k >> 3) * 16 + nc) * 8 + (k & 7)] = (_Float16)val;
        return;
    }
    if (bi < OFF_EMB) {
        // ---- prep_bpk: B in MFMA B-fragment order, f16, x log2e ----
        // column regions: [cheS|vdwS|cheY|vdwY]
        int i = (bi - OFF_BPK) * 256 + tid;     // exactly NCONV*128*1024
        int l = i >> 17;
        int rem = i & 131071;
        int k = rem >> 10;
        int c = rem & 1023;
        int half = (c >> 8) & 1;
        const float* src = half ? vgW : cgW;
        int grow = l * 384 + ((c < 512) ? k : 256 + k);
        float val = src[(size_t)grow * 256 + (c & 255)] * LOG2E_F;
        int nt = c >> 4, nc = c & 15;
        int s = k >> 5, kq = (k >> 3) & 3, j = k & 7;
        bpk[(size_t)l * 131072 + (((size_t)nt * 4 + s) * 64 + kq * 16 + nc) * 8 + j] = (_Float16)val;
        return;
    }
    if (bi < OFF_RBF) {
        // ---- embed: f32 nodes + f16 copy; 2 nodes per 256-thread block ----
        int n = (bi - OFF_EMB) * 2 + (tid >> 7);
        int t = tid & 127;
        const float* arow = atoms + (size_t)n * 13;
        float acc = embB[t];
        #pragma unroll
        for (int k = 0; k < 13; ++k) acc = fmaf(arow[k], embW[k * HH + t], acc);
        nodes[(size_t)n * HH + t] = acc;
        nodes_h[(size_t)n * HH + t] = (_Float16)acc;
        return;
    }
    {
        // ---- rbf: per-node A-fragment order, compact 640-f16 stride ----
        // tile0 (rows 0..15): [lane(64)][8] at 0; tile1c (rows 16..19):
        // [quad][row-16][8] at 512. Rows 20..31 of tile1 not stored.
        // HW trig: rev = d/(2*cutoff) in [0,0.55] — no range reduction.
        int i = (bi - OFF_RBF) * 256 + tid;     // exactly 2*NN*MM
        bool isv = i >= NN * MM;
        int rem = isv ? i - NN * MM : i;
        int n = rem / MM, m = rem % MM;
        float d = isv ? vdw_fea[rem] : che_fea[rem];
        float cutoff = isv ? VDW_CUT : CHE_CUT;
        float rev = d * (0.5f / cutoff);
        float s1 = sin_rev_(rev);
        float c1 = cos_rev_(rev);
        float env = 0.5f * (c1 + 1.f);
        float scale = (d < cutoff) ? (env / d) : 0.f;
        float out[EE];
        float skm1 = 0.f, sk = s1;
        #pragma unroll
        for (int e = 0; e < EE; ++e) {
            out[e] = sk * scale;
            float nx = 2.f * c1 * sk - skm1;
            skm1 = sk; sk = nx;
        }
        _Float16* rf = rfrag + (size_t)(isv ? NN + n : n) * 640;
        f16x8 v0, v1, v2, v3;
        #pragma unroll
        for (int j = 0; j < 8; ++j) {
            v0[j] = (_Float16)out[j];
            v1[j] = (_Float16)out[8 + j];
            v2[j] = (j < 4) ? (_Float16)out[16 + j] : (_Float16)0.f;
            v3[j] = (_Float16)0.f;
        }
        if (m < 16) {
            _Float16* base = rf + m * 8;
            *(f16x8*)(base) = v0;             // quad 0 (k 0..7)
            *(f16x8*)(base + 128) = v1;       // quad 1 (k 8..15)
            *(f16x8*)(base + 256) = v2;       // quad 2 (k 16..23, 20+ zero)
            *(f16x8*)(base + 384) = v3;       // quad 3 (k 24..31, zero)
        } else {
            _Float16* base = rf + 512 + (m - 16) * 8;
            *(f16x8*)(base) = v0;
            *(f16x8*)(base + 32) = v1;
            *(f16x8*)(base + 64) = v2;
            *(f16x8*)(base + 96) = v3;
        }
        return;
    }
}

// ---------------- SY GEMM via MFMA: [N,128]@[128,1024] -> Spk + Ypk f16x2 ---
// 625 blocks x 4 waves; M=32 rows/block, 2 row-tiles per wave. Wave wv
// handles gate pair tiles (wv*16+p, wv*16+8+p), p=0..7 -> (filt,core) of one
// channel in SAME lane. wv 0: che-S, 1: vdw-S, 2: che-Y, 3: vdw-Y.
//
// R5/R6: p-loop unrolled x2 with ALTERNATING B-fragment buffers (fb0/cb0 vs
// fb1/cb1) — removes 32 v_mov per p-step and gives full-tile-deep prefetch.
// All values pre-scaled by log2e.
#define GEMM_TILE(P, FB, CB)                                                     \
    do {                                                                          \
        f32x4 a0f = {0.f,0.f,0.f,0.f}, a0c = {0.f,0.f,0.f,0.f};                   \
        f32x4 a1f = {0.f,0.f,0.f,0.f}, a1c = {0.f,0.f,0.f,0.f};                   \
        _Pragma("unroll")                                                         \
        for (int s = 0; s < 4; ++s) {                                             \
            a0f = __builtin_amdgcn_mfma_f32_16x16x32_f16(af0[s], FB[s], a0f, 0, 0, 0); \
            a0c = __builtin_amdgcn_mfma_f32_16x16x32_f16(af0[s], CB[s], a0c, 0, 0, 0); \
            a1f = __builtin_amdgcn_mfma_f32_16x16x32_f16(af1[s], FB[s], a1f, 0, 0, 0); \
            a1c = __builtin_amdgcn_mfma_f32_16x16x32_f16(af1[s], CB[s], a1c, 0, 0, 0); \
        }                                                                         \
        int row_ = m0 + quad * 4;                                                 \
        int word_ = wbase + (P) * 16;                                             \
        _Pragma("unroll")                                                         \
        for (int i = 0; i < 4; ++i) {                                             \
            dst[(size_t)(row_ + i) * 256 + word_] = __builtin_amdgcn_cvt_pkrtz(a0f[i], a0c[i]); \
            dst[(size_t)(row_ + 16 + i) * 256 + word_] = __builtin_amdgcn_cvt_pkrtz(a1f[i], a1c[i]); \
        }                                                                         \
    } while (0)

__global__ __launch_bounds__(256)
void gemm_mfma(const _Float16* __restrict__ Ah, const _Float16* __restrict__ Bpk,
               half2_t* __restrict__ Spk, half2_t* __restrict__ Ypk) {
    int lane = threadIdx.x & 63;
    int wv = threadIdx.x >> 6;       // 0..3
    int m0 = blockIdx.x * 32;
    int la = lane & 15;
    int quad = lane >> 4;
    int k0 = quad * 8;

    f16x8 af0[4], af1[4];
    {
        const _Float16* arow = Ah + (size_t)(m0 + la) * 128 + k0;
        #pragma unroll
        for (int s = 0; s < 4; ++s) {
            af0[s] = *(const f16x8*)(arow + s * 32);
            af1[s] = *(const f16x8*)(arow + 2048 + s * 32);   // rows m0+16..m0+31
        }
    }

    const f16x8* bp = (const f16x8*)Bpk;
    int ntf0 = wv * 16;
    half2_t* dst = (wv & 2) ? Ypk : Spk;
    int wbase = (wv & 1) * 128 + la;

    f16x8 fb0[4], cb0[4], fb1[4], cb1[4];
    #pragma unroll
    for (int s = 0; s < 4; ++s) {                      // tile p=0 -> buf0
        fb0[s] = bp[((size_t)ntf0 * 4 + s) * 64 + lane];
        cb0[s] = bp[((size_t)(ntf0 + 8) * 4 + s) * 64 + lane];
    }
    #pragma unroll
    for (int pp = 0; pp < 4; ++pp) {
        int p0 = 2 * pp, p1 = 2 * pp + 1;
        #pragma unroll
        for (int s = 0; s < 4; ++s) {                  // prefetch p1 -> buf1
            fb1[s] = bp[((size_t)(ntf0 + p1) * 4 + s) * 64 + lane];
            cb1[s] = bp[((size_t)(ntf0 + 8 + p1) * 4 + s) * 64 + lane];
        }
        GEMM_TILE(p0, fb0, cb0);
        if (pp < 3) {
            #pragma unroll
            for (int s = 0; s < 4; ++s) {              // prefetch p0+2 -> buf0
                fb0[s] = bp[((size_t)(ntf0 + p0 + 2) * 4 + s) * 64 + lane];
                cb0[s] = bp[((size_t)(ntf0 + 10 + p0) * 4 + s) * 64 + lane];
            }
        }
        GEMM_TILE(p1, fb1, cb1);
    }
}

// ---------------- fused edge: MFMA contraction + LDS + gate + update --------
// Per block: one node, 4 WAVES (256 threads). Phase 1: 16 (half,pg)
// tile-pairs split across 4 waves -> G2. One barrier. Phase 2: threads
// t<128 handle 20 che edges of channel t; t>=128 the 20 vdw edges.
//
// R4 latency structure: 4-deep register pipeline for the Y-gathers.
// R6 LDS: G2P=256 exactly; red[] aliased onto G2 (extra barrier) -> 20480 B
// -> 8 blocks/CU. R8: gather byte-offsets jo[m] = (jx[m]<<10) + h2*512 +
// tc*4 precomputed ONCE; each gather is then a single 32-bit-voffset load
// off the uniform Ypk base (saves ~2 VALU per gather).
//
// STATUS (R7 counters): VALUBusy 82%, 0 bank conflicts, VGPR 32, occ 79%.
// Edge is near its transcendental+VALU issue floor.
//
// NaN guard: p = med3(p_raw, gc, 25). Equivalent to `(gc>24)? gc : p` for
// all finite gc; keeps the fmaf(inf, 0, acc) NaN path (R15) impossible.
#define G2P 256   // half2 pitch per group-row — MUST be >= 256
__global__ __launch_bounds__(256, 8)
void edge_kernel(const float* __restrict__ nodes_in, float* __restrict__ nodes_out,
                 _Float16* __restrict__ nodes_h,
                 const half2_t* __restrict__ Spk, const half2_t* __restrict__ Ypk,
                 const _Float16* __restrict__ rfrag,
                 const int* __restrict__ idx_che, const int* __restrict__ idx_vdw,
                 const _Float16* __restrict__ bwc,  // this layer: [2][16][64][8]
                 const float* __restrict__ bC) {    // [2][256]
    __shared__ __align__(16) unsigned char smem[20 * G2P * 4]; // 20480 B total
    half2_t* G2 = (half2_t*)smem;
    float* red = (float*)smem;                       // aliased; see barrier note
    int t = threadIdx.x;                            // 0..255
    int lane = t & 63;
    int wv = t >> 6;                                // 0..3
    int n = blockIdx.x;
    int h2 = t >> 7;                                // 0 = che group, 1 = vdw
    int tc = t & 127;                               // channel

    // ---- per-group neighbor indices: 5 x dwordx4; fold into byte offsets --
    const int* idxp = h2 ? (idx_vdw + (size_t)n * MM) : (idx_che + (size_t)n * MM);
    unsigned int jo[MM];
    {
        int jx[MM];
        const int4* ip = (const int4*)idxp;
        #pragma unroll
        for (int k = 0; k < 5; ++k) *(int4*)&jx[k * 4] = ip[k];
        unsigned int tcoff = (unsigned int)(h2 * 512 + tc * 4);
        #pragma unroll
        for (int m = 0; m < MM; ++m) jo[m] = ((unsigned int)jx[m] << 10) + tcoff;
    }
    const char* ybase = (const char*)Ypk;

    // ---- pipeline prologue: first 4 Y-gathers issue before phase 1 ----
    half2_t y0 = *(const half2_t*)(ybase + jo[0]);
    half2_t y1 = *(const half2_t*)(ybase + jo[1]);
    half2_t y2 = *(const half2_t*)(ybase + jo[2]);
    half2_t y3 = *(const half2_t*)(ybase + jo[3]);

    half2_t spx = Spk[(size_t)n * 256 + h2 * 128 + tc];
    float old = (h2 == 0) ? nodes_in[(size_t)n * HH + tc] : 0.f;
    float sf = bC[h2 * 256 + tc] + (float)spx.x;
    float sc = bC[h2 * 256 + 128 + tc] + (float)spx.y;

    const half2_t ONE0 = {(__fp16)1.f, (__fp16)0.f};
    const half2_t ZERO1 = {(__fp16)0.f, (__fp16)1.f};
    int quad = lane >> 4;
    int cla = lane & 15;

    // ---- phase 1: wave wv computes half hw = wv>>1, tiles pg = (wv&1)*4+p
    {
        int hw = wv >> 1;
        const _Float16* rf = rfrag + (size_t)(hw * NN + n) * 640;
        f16x8 a0 = *(const f16x8*)(rf + lane * 8);
        f16x8 a1 = {};
        if (cla < 4) a1 = *(const f16x8*)(rf + 512 + (quad * 4 + cla) * 8);
        const f16x8* bw = (const f16x8*)bwc + ((size_t)hw * 16) * 64;
        #pragma unroll
        for (int p = 0; p < 4; ++p) {
            int pg = (wv & 1) * 4 + p;              // 0..7
            f16x8 bf = bw[(size_t)pg * 64 + lane];
            f16x8 bcfr = bw[(size_t)(8 + pg) * 64 + lane];
            f32x4 g0f = {0.f, 0.f, 0.f, 0.f};
            f32x4 g0c = {0.f, 0.f, 0.f, 0.f};
            f32x4 g1f = {0.f, 0.f, 0.f, 0.f};
            f32x4 g1c = {0.f, 0.f, 0.f, 0.f};
            g0f = __builtin_amdgcn_mfma_f32_16x16x32_f16(a0, bf, g0f, 0, 0, 0);
            g0c = __builtin_amdgcn_mfma_f32_16x16x32_f16(a0, bcfr, g0c, 0, 0, 0);
            g1f = __builtin_amdgcn_mfma_f32_16x16x32_f16(a1, bf, g1f, 0, 0, 0);
            g1c = __builtin_amdgcn_mfma_f32_16x16x32_f16(a1, bcfr, g1c, 0, 0, 0);
            int col = pg * 16 + cla;                // = channel col, 0..127
            // rows quad*4+i -> (g = hw*10 + quad*2 + (i>>1), parity i&1)
            half4_t w0;
            half2_t p0 = __builtin_amdgcn_cvt_pkrtz(g0f[0], g0c[0]);
            half2_t p1 = __builtin_amdgcn_cvt_pkrtz(g0f[1], g0c[1]);
            w0.x = p0.x; w0.y = p0.y; w0.z = p1.x; w0.w = p1.y;
            *(half4_t*)&G2[(hw * 10 + quad * 2) * G2P + col * 2] = w0;
            half4_t w1;
            half2_t p2 = __builtin_amdgcn_cvt_pkrtz(g0f[2], g0c[2]);
            half2_t p3 = __builtin_amdgcn_cvt_pkrtz(g0f[3], g0c[3]);
            w1.x = p2.x; w1.y = p2.y; w1.z = p3.x; w1.w = p3.y;
            *(half4_t*)&G2[(hw * 10 + quad * 2 + 1) * G2P + col * 2] = w1;
            if (quad == 0) {                        // rows 16..19 -> g 8,9
                half4_t w2;
                half2_t q0 = __builtin_amdgcn_cvt_pkrtz(g1f[0], g1c[0]);
                half2_t q1 = __builtin_amdgcn_cvt_pkrtz(g1f[1], g1c[1]);
                w2.x = q0.x; w2.y = q0.y; w2.z = q1.x; w2.w = q1.y;
                *(half4_t*)&G2[(hw * 10 + 8) * G2P + col * 2] = w2;
                half4_t w3;
                half2_t q2 = __builtin_amdgcn_cvt_pkrtz(g1f[2], g1c[2]);
                half2_t q3 = __builtin_amdgcn_cvt_pkrtz(g1f[3], g1c[3]);
                w3.x = q2.x; w3.y = q2.y; w3.z = q3.x; w3.w = q3.y;
                *(half4_t*)&G2[(hw * 10 + 9) * G2P + col * 2] = w3;
            }
        }
    }
    __syncthreads();

    // ---- phase 2: 20 edges, 4-deep software-pipelined gathers ----
    float acc = 0.f;
    const half2_t* gq = G2 + (h2 * 10) * G2P + tc * 2;
    #pragma unroll
    for (int cb = 0; cb < 5; ++cb) {
        half2_t n0 = {}, n1 = {}, n2 = {}, n3 = {};
        if (cb < 4) {                               // prefetch next 4 edges
            n0 = *(const half2_t*)(ybase + jo[cb * 4 + 4]);
            n1 = *(const half2_t*)(ybase + jo[cb * 4 + 5]);
            n2 = *(const half2_t*)(ybase + jo[cb * 4 + 6]);
            n3 = *(const half2_t*)(ybase + jo[cb * 4 + 7]);
        }
        half4_t gp0 = *(const half4_t*)(gq + (size_t)(2 * cb) * G2P);     // edges 4cb,4cb+1
        half4_t gp1 = *(const half4_t*)(gq + (size_t)(2 * cb + 1) * G2P); // edges 4cb+2,4cb+3
        half2_t gw0 = half2_t{gp0.x, gp0.y} + y0;
        half2_t gw1 = half2_t{gp0.z, gp0.w} + y1;
        half2_t gw2 = half2_t{gp1.x, gp1.y} + y2;
        half2_t gw3 = half2_t{gp1.z, gp1.w} + y3;
        float gf0 = fdot2_(gw0, ONE0, sf), gc0 = fdot2_(gw0, ZERO1, sc);
        float gf1 = fdot2_(gw1, ONE0, sf), gc1 = fdot2_(gw1, ZERO1, sc);
        float gf2 = fdot2_(gw2, ONE0, sf), gc2 = fdot2_(gw2, ZERO1, sc);
        float gf3 = fdot2_(gw3, ONE0, sf), gc3 = fdot2_(gw3, ZERO1, sc);
        float u0 = rcp_(1.f + exp2_(-gf0));
        float u1 = rcp_(1.f + exp2_(-gf1));
        float u2 = rcp_(1.f + exp2_(-gf2));
        float u3 = rcp_(1.f + exp2_(-gf3));
        float p0 = med3_(log2_(1.f + exp2_(gc0)), gc0, 25.f);
        float p1 = med3_(log2_(1.f + exp2_(gc1)), gc1, 25.f);
        float p2 = med3_(log2_(1.f + exp2_(gc2)), gc2, 25.f);
        float p3 = med3_(log2_(1.f + exp2_(gc3)), gc3, 25.f);
        acc = fmaf(p0, u0, acc);
        acc = fmaf(p1, u1, acc);
        acc = fmaf(p2, u2, acc);
        acc = fmaf(p3, u3, acc);
        y0 = n0; y1 = n1; y2 = n2; y3 = n3;
    }
    // red[] aliases G2 — this barrier guarantees every thread's G2 reads
    // completed before any vdw thread overwrites the storage.
    __syncthreads();
    if (h2) red[tc] = acc;
    __syncthreads();
    if (!h2) {
        float res = sp_(fmaf(acc + red[tc], LN2_F, old));
        nodes_out[(size_t)n * HH + tc] = res;
        nodes_h[(size_t)n * HH + tc] = (_Float16)res;
    }
}

// ---------------- pooling + head MLP ---------------------------------------
// R7: parallel prefix for start offsets + LDS tree reductions (the serial
// per-block prefix and t==0 final sum were dependent-load chains).
__global__ void pool_kernel(const float* __restrict__ nodes, const int* __restrict__ num_atoms,
                            const float* __restrict__ fc1_W, const float* __restrict__ fc1_b,
                            const float* __restrict__ out_W, const float* __restrict__ out_b,
                            float* __restrict__ out) {
    __shared__ float sh[HH];
    __shared__ float red[HH];
    __shared__ int ipart[HH];
    int b = blockIdx.x, t = threadIdx.x;

    // ---- parallel prefix: start = sum_{i<b} num_atoms[i] ----
    int s = 0;
    for (int i = t; i < b; i += HH) s += num_atoms[i];
    ipart[t] = s;
    __syncthreads();
    #pragma unroll
    for (int st = HH / 2; st > 0; st >>= 1) {
        if (t < st) ipart[t] += ipart[t + st];
        __syncthreads();
    }
    int start = ipart[0];
    int cnt = num_atoms[b];

    float sum = 0.f;
    for (int a = 0; a < cnt; ++a) sum += nodes[(size_t)(start + a) * HH + t];
    float mean = sum / (float)cnt;
    sh[t] = sp_(mean);
    __syncthreads();
    float o = fc1_b[t];
    #pragma unroll 4
    for (int k = 0; k < HH; ++k) o = fmaf(sh[k], fc1_W[k * HH + t], o);
    red[t] = sp_(o) * out_W[t];
    __syncthreads();
    #pragma unroll
    for (int st = HH / 2; st > 0; st >>= 1) {
        if (t < st) red[t] += red[t + st];
        __syncthreads();
    }
    if (t == 0) out[b] = red[0] + out_b[0];
}

// ---------------- launch ----------------------------------------------------
extern "C" void kernel_launch(void* const* d_in, const int* in_sizes, int n_in,
                              void* d_out, int out_size, void* d_ws, size_t ws_size,
                              hipStream_t stream) {
    const float* atoms_embed   = (const float*)d_in[0];
    const float* che_nbrs_fea  = (const float*)d_in[1];
    const float* vdw_nbrs_fea  = (const float*)d_in[2];
    const int*   che_nbrs_idx  = (const int*)  d_in[3];
    const int*   vdw_nbrs_idx  = (const int*)  d_in[4];
    const int*   num_atoms     = (const int*)  d_in[5];
    const float* emb_W         = (const float*)d_in[6];
    const float* emb_b         = (const float*)d_in[7];
    const float* che_filter_W  = (const float*)d_in[8];
    const float* che_filter_b  = (const float*)d_in[9];
    const float* che_fc_W      = (const float*)d_in[10];
    const float* che_fc_b      = (const float*)d_in[11];
    const float* vdw_filter_W  = (const float*)d_in[12];
    const float* vdw_filter_b  = (const float*)d_in[13];
    const float* vdw_fc_W      = (const float*)d_in[14];
    const float* vdw_fc_b      = (const float*)d_in[15];
    const float* fc1_W         = (const float*)d_in[16];
    const float* fc1_b         = (const float*)d_in[17];
    const float* out_W         = (const float*)d_in[18];
    const float* out_b         = (const float*)d_in[19];
    float* out = (float*)d_out;

    // workspace layout (~130 MB)
    float* w = (float*)d_ws;
    float* nodesA   = w;                                       // NN*HH f32
    float* nodesB   = nodesA + (size_t)NN * HH;                // NN*HH f32
    _Float16* nodes_h = (_Float16*)(nodesB + (size_t)NN * HH); // NN*HH f16
    half2_t* Spk    = (half2_t*)(nodes_h + (size_t)NN * HH);   // NN*256 words
    half2_t* Ypk    = Spk + (size_t)NN * 256;                  // NN*256 words
    _Float16* rfrag = (_Float16*)(Ypk + (size_t)NN * 256);     // 2*NN*640 f16
    _Float16* bpk   = rfrag + (size_t)2 * NN * 640;            // NCONV*131072 f16
    _Float16* bwc   = bpk + (size_t)NCONV * 131072;            // NCONV*2*16*512 f16
    float* bc       = (float*)(bwc + (size_t)NCONV * 2 * 16 * 512); // NCONV*512 f32

    // ONE front-end launch (was 5): bias + bwc + bpk + embed + rbf
    mega_prep<<<MB_TOTAL, 256, 0, stream>>>(
        che_filter_b, che_fc_W, che_fc_b, vdw_filter_b, vdw_fc_W, vdw_fc_b,
        che_filter_W, vdw_filter_W,
        atoms_embed, emb_W, emb_b, che_nbrs_fea, vdw_nbrs_fea,
        bc, bwc, bpk, nodesA, nodes_h, rfrag);

    float* cur = nodesA;
    float* nxt = nodesB;
    for (int l = 0; l < NCONV; ++l) {
        gemm_mfma<<<NN / 32, 256, 0, stream>>>(nodes_h, bpk + (size_t)l * 131072, Spk, Ypk);
        edge_kernel<<<NN, 256, 0, stream>>>(
            cur, nxt, nodes_h, Spk, Ypk, rfrag, che_nbrs_idx, vdw_nbrs_idx,
            bwc + (size_t)l * 2 * 16 * 512, bc + (size_t)l * 512);
        float* tmp = cur; cur = nxt; nxt = tmp;
    }

    pool_kernel<<<BB, HH, 0, stream>>>(cur, num_atoms, fc1_W, fc1_b, out_W, out_b, out);
}